// Round 9
// baseline (213.072 us; speedup 1.0000x reference)
//
#include <hip/hip_runtime.h>
#include <cstdint>

#define NPTS   4096
#define NBATCH 1024
#define NIT    10
#define TPB    512
#define PPT    8      // points per thread at 512 threads

// ---------------- threefry2x32 (exact JAX rounds) ----------------
__host__ __device__ inline uint32_t rotl32(uint32_t v, uint32_t r){ return (v<<r)|(v>>(32u-r)); }

__host__ __device__ inline void tf2x32(uint32_t k0,uint32_t k1,uint32_t x0,uint32_t x1,
                                       uint32_t&o0,uint32_t&o1){
  uint32_t ks2 = k0 ^ k1 ^ 0x1BD11BDAu;
  x0 += k0; x1 += k1;
  x0+=x1; x1=rotl32(x1,13); x1^=x0;
  x0+=x1; x1=rotl32(x1,15); x1^=x0;
  x0+=x1; x1=rotl32(x1,26); x1^=x0;
  x0+=x1; x1=rotl32(x1, 6); x1^=x0;
  x0+=k1; x1+=ks2+1u;
  x0+=x1; x1=rotl32(x1,17); x1^=x0;
  x0+=x1; x1=rotl32(x1,29); x1^=x0;
  x0+=x1; x1=rotl32(x1,16); x1^=x0;
  x0+=x1; x1=rotl32(x1,24); x1^=x0;
  x0+=ks2; x1+=k0+2u;
  x0+=x1; x1=rotl32(x1,13); x1^=x0;
  x0+=x1; x1=rotl32(x1,15); x1^=x0;
  x0+=x1; x1=rotl32(x1,26); x1^=x0;
  x0+=x1; x1=rotl32(x1, 6); x1^=x0;
  x0+=k0; x1+=k1+3u;
  x0+=x1; x1=rotl32(x1,17); x1^=x0;
  x0+=x1; x1=rotl32(x1,29); x1^=x0;
  x0+=x1; x1=rotl32(x1,16); x1^=x0;
  x0+=x1; x1=rotl32(x1,24); x1^=x0;
  x0+=k1; x1+=ks2+4u;
  x0+=x1; x1=rotl32(x1,13); x1^=x0;
  x0+=x1; x1=rotl32(x1,15); x1^=x0;
  x0+=x1; x1=rotl32(x1,26); x1^=x0;
  x0+=x1; x1=rotl32(x1, 6); x1^=x0;
  x0+=ks2; x1+=k0+5u;
  o0=x0; o1=x1;
}

// ---------------- math helpers ----------------
__device__ inline float errsq_f(const float H[9], float x, float y, float kx, float ky){
  float z  = H[6]*x + H[7]*y + H[8];
  float zi = (fabsf(z) > 1e-8f) ? (1.0f/z) : 1.0f;
  float px = (H[0]*x + H[1]*y + H[2])*zi;
  float py = (H[3]*x + H[4]*y + H[5])*zi;
  float dx = px - kx, dy = py - ky;
  return dx*dx + dy*dy;
}

__device__ inline void denorm_h(const double h[9], double s1, double m1x, double m1y,
                                double s2, double m2x, double m2y, float out[9]){
  double G[3][3];
  #pragma unroll
  for(int r=0;r<3;r++){
    double h0=h[3*r], h1=h[3*r+1], h2=h[3*r+2];
    G[r][0] = h0*s1;
    G[r][1] = h1*s1;
    G[r][2] = -s1*m1x*h0 - s1*m1y*h1 + h2;
  }
  double Hm[3][3];
  double inv2 = 1.0/s2;
  #pragma unroll
  for(int c=0;c<3;c++){
    Hm[0][c] = G[0][c]*inv2 + m2x*G[2][c];
    Hm[1][c] = G[1][c]*inv2 + m2y*G[2][c];
    Hm[2][c] = G[2][c];
  }
  double invd = 1.0/(Hm[2][2] + 1e-8);
  #pragma unroll
  for(int r=0;r<3;r++)
    #pragma unroll
    for(int c=0;c<3;c++)
      out[3*r+c] = (float)(Hm[r][c]*invd);
}

__device__ inline double det3c(double ax,double ay, double bx,double by, double cx,double cy){
  return ax*(by-cy) - bx*(ay-cy) + cx*(ay-by);
}

__device__ inline void h4pt(const double P[4][2], double M[3][3]){
  double c0 = det3c(P[3][0],P[3][1], P[1][0],P[1][1], P[2][0],P[2][1]);
  double c1 = det3c(P[0][0],P[0][1], P[3][0],P[3][1], P[2][0],P[2][1]);
  double c2 = det3c(P[0][0],P[0][1], P[1][0],P[1][1], P[3][0],P[3][1]);
  M[0][0]=c0*P[0][0]; M[0][1]=c1*P[1][0]; M[0][2]=c2*P[2][0];
  M[1][0]=c0*P[0][1]; M[1][1]=c1*P[1][1]; M[1][2]=c2*P[2][1];
  M[2][0]=c0;         M[2][1]=c1;         M[2][2]=c2;
}

__device__ inline void adj3(const double M[3][3], double A[3][3]){
  A[0][0]=M[1][1]*M[2][2]-M[1][2]*M[2][1];
  A[0][1]=M[0][2]*M[2][1]-M[0][1]*M[2][2];
  A[0][2]=M[0][1]*M[1][2]-M[0][2]*M[1][1];
  A[1][0]=M[1][2]*M[2][0]-M[1][0]*M[2][2];
  A[1][1]=M[0][0]*M[2][2]-M[0][2]*M[2][0];
  A[1][2]=M[0][2]*M[1][0]-M[0][0]*M[1][2];
  A[2][0]=M[1][0]*M[2][1]-M[1][1]*M[2][0];
  A[2][1]=M[0][1]*M[2][0]-M[0][0]*M[2][1];
  A[2][2]=M[0][0]*M[1][1]-M[0][1]*M[1][0];
}

__device__ inline void ins4(uint64_t b[4], uint64_t k){
  if(k > b[0]){ b[3]=b[2]; b[2]=b[1]; b[1]=b[0]; b[0]=k; }
  else if(k > b[1]){ b[3]=b[2]; b[2]=b[1]; b[1]=k; }
  else if(k > b[2]){ b[3]=b[2]; b[2]=k; }
  else if(k > b[3]){ b[3]=k; }
}

// symmetric 3x3 explicit inverse (reads lower triangle)
__device__ inline void inv3sym(const double A[3][3], double R[3][3]){
  double a=A[0][0], b=A[1][0], c=A[2][0], d=A[1][1], e=A[2][1], f=A[2][2];
  double C00=d*f-e*e, C01=c*e-b*f, C02=b*e-c*d;
  double det=a*C00+b*C01+c*C02;
  if(det < 1e-300) det = 1e-300;   // SPD in practice
  double id=1.0/det;
  R[0][0]=C00*id; R[0][1]=C01*id; R[0][2]=C02*id;
  R[1][0]=C01*id; R[1][1]=(a*f-c*c)*id; R[1][2]=(b*c-a*e)*id;
  R[2][0]=C02*id; R[2][1]=R[1][2];      R[2][2]=(a*d-b*b)*id;
}
__device__ inline void mv3(const double M[3][3], const double x[3], double y[3]){
  y[0]=M[0][0]*x[0]+M[0][1]*x[1]+M[0][2]*x[2];
  y[1]=M[1][0]*x[0]+M[1][1]*x[1]+M[1][2]*x[2];
  y[2]=M[2][0]*x[0]+M[2][1]*x[1]+M[2][2]*x[2];
}

// DLT solve from 24 reduced sums: explicit-inverse block solve (f64, one thread)
__device__ inline void solve24x(const double* sMd, float curHn[9], float curH[9],
                                bool dnorm, double ns1,double nm1x,double nm1y,
                                double ns2,double nm2x,double nm2y){
  double S0[3][3],S1[3][3],S2[3][3],S3[3][3];
  auto unpackd=[&](const double* s, double M[3][3]){
    M[0][0]=s[0]; M[0][1]=s[1]; M[0][2]=s[3];
    M[1][0]=s[1]; M[1][1]=s[2]; M[1][2]=s[4];
    M[2][0]=s[3]; M[2][1]=s[4]; M[2][2]=s[5];
  };
  unpackd(sMd+0,S0); unpackd(sMd+6,S1); unpackd(sMd+12,S2); unpackd(sMd+18,S3);

  double S0i[3][3]; inv3sym(S0,S0i);
  double T1[3][3], T2[3][3];
  #pragma unroll
  for(int i=0;i<3;i++)
    #pragma unroll
    for(int j=0;j<3;j++){
      T1[i][j]=S0i[i][0]*S1[0][j]+S0i[i][1]*S1[1][j]+S0i[i][2]*S1[2][j];
      T2[i][j]=S0i[i][0]*S2[0][j]+S0i[i][1]*S2[1][j]+S0i[i][2]*S2[2][j];
    }
  double Sc[3][3];
  #pragma unroll
  for(int i=0;i<3;i++)
    #pragma unroll
    for(int j=0;j<3;j++){
      double s = S3[i][j];
      #pragma unroll
      for(int k=0;k<3;k++) s -= S1[i][k]*T1[k][j] + S2[i][k]*T2[k][j];
      Sc[i][j]=s;
    }
  double Sci[3][3]; inv3sym(Sc,Sci);

  double v[9];
  #pragma unroll
  for(int i=0;i<9;i++) v[i]=1.0;
  #pragma unroll
  for(int itn=0; itn<2; itn++){
    double a[3]={v[0],v[1],v[2]}, b[3]={v[3],v[4],v[5]}, c[3]={v[6],v[7],v[8]};
    double w1[3],w2[3];
    mv3(S0i,a,w1); mv3(S0i,b,w2);
    double rhs[3];
    #pragma unroll
    for(int j=0;j<3;j++)
      rhs[j] = c[j] + T1[0][j]*a[0]+T1[1][j]*a[1]+T1[2][j]*a[2]
                    + T2[0][j]*b[0]+T2[1][j]*b[1]+T2[2][j]*b[2];
    double rr[3];
    mv3(Sci,rhs,rr);
    #pragma unroll
    for(int i=0;i<3;i++){
      v[i]   = w1[i] + T1[i][0]*rr[0]+T1[i][1]*rr[1]+T1[i][2]*rr[2];
      v[3+i] = w2[i] + T2[i][0]*rr[0]+T2[i][1]*rr[1]+T2[i][2]*rr[2];
      v[6+i] = rr[i];
    }
    if(itn==0){
      double mx=0.0;
      #pragma unroll
      for(int i=0;i<9;i++){ double aa=fabs(v[i]); if(aa>mx) mx=aa; }
      double sc = 1.0/(mx + 1e-300);
      #pragma unroll
      for(int i=0;i<9;i++) v[i]*=sc;
    }
  }
  double n2=0.0;
  #pragma unroll
  for(int i=0;i<9;i++) n2 += v[i]*v[i];
  double invn = 1.0/sqrt(n2);
  #pragma unroll
  for(int i=0;i<9;i++) v[i]*=invn;
  #pragma unroll
  for(int j=0;j<9;j++) curHn[j]=(float)v[j];
  if(dnorm) denorm_h(v, ns1,nm1x,nm1y, ns2,nm2x,nm2y, curH);
}

// 4-point analytic model + validity (one thread)
__device__ inline void model4(const double P1[4][2], const double P2[4][2],
                              float Hf[9], int* flag){
  const int TRI[4][3] = {{0,1,2},{0,1,3},{0,2,3},{1,2,3}};
  bool valid = true;
  #pragma unroll
  for(int tq=0;tq<4;tq++){
    const int i0=TRI[tq][0], i1=TRI[tq][1], i2=TRI[tq][2];
    double d1 = det3c(P1[i0][0],P1[i0][1], P1[i1][0],P1[i1][1], P1[i2][0],P1[i2][1]);
    double d2 = det3c(P2[i0][0],P2[i0][1], P2[i1][0],P2[i1][1], P2[i2][0],P2[i2][1]);
    int s1 = (d1>0.0)-(d1<0.0), s2 = (d2>0.0)-(d2<0.0);
    if(s1 != s2) valid = false;
  }
  double MA[3][3], MB[3][3], AJ[3][3], H[3][3];
  h4pt(P1, MA); h4pt(P2, MB);
  adj3(MA, AJ);
  #pragma unroll
  for(int i=0;i<3;i++)
    #pragma unroll
    for(int j=0;j<3;j++)
      H[i][j] = MB[i][0]*AJ[0][j] + MB[i][1]*AJ[1][j] + MB[i][2]*AJ[2][j];
  double n2=0.0;
  #pragma unroll
  for(int i=0;i<3;i++)
    #pragma unroll
    for(int j=0;j<3;j++) n2 += H[i][j]*H[i][j];
  double invn = 1.0/sqrt(n2);
  double invd = 1.0/(H[2][2]*invn + 1e-8);
  #pragma unroll
  for(int i=0;i<3;i++)
    #pragma unroll
    for(int j=0;j<3;j++) Hf[3*i+j] = (float)(H[i][j]*invn*invd);
  bool diag_ok = (fminf(fminf(fabsf(Hf[0]),fabsf(Hf[4])),fabsf(Hf[8])) > 1e-4f);
  *flag = (valid && diag_ok) ? 1 : 0;
}

// ---------------- shared-memory overlay ----------------
struct ShSample {
  unsigned long long ls2[4][TPB];   // column-major: lane stride 8B -> 2-way (free)
  float sH[9];
  int   sFlag;
  int   redi[8];
  int   sdone;
};
struct ShPolish {
  float  p2b[TPB][28];              // 57 KB (rows 112B, 16B-aligned)
  double p3[16][25];
  double sMd[24];
  unsigned long long redu[8];
  int    redi[8];
  float  sScore;
  float  sModel[9];
  float  curHn[9];
  float  curH[9];
};
struct ShInit {
  double arr[TPB][4];
  double res[4];
};
union ShAll { ShSample s; ShPolish p; ShInit i; };

// ---------------- polish(pi): one 512-thread block ----------------
__device__ void do_polish(ShPolish& sp, float* stateF, const float* nrm,
                          const float* scores, const float* models,
                          const float* kp1, const float* kp2,
                          float* best_inl, int pi){
  const int t = threadIdx.x;
  const int lane = t & 63, wv = t >> 6;

  if(stateF[1] != 0.0f) return;   // done committed by previous kernel — uniform

  // argmax over 1024 scores (first-index tie-break)
  uint64_t k;
  {
    float sA = scores[t], sB = scores[t+512];
    uint64_t kA = ((uint64_t)(uint32_t)(int)(sA + 2.0f) << 12) | (uint64_t)(1023 - t);
    uint64_t kB = ((uint64_t)(uint32_t)(int)(sB + 2.0f) << 12) | (uint64_t)(1023 - (t+512));
    k = (kA >= kB) ? kA : kB;
  }
  #pragma unroll
  for(int off=32; off>=1; off>>=1){
    uint64_t o = __shfl_down(k, off, 64);
    if(o > k) k = o;
  }
  if(lane==0) sp.redu[wv]=k;
  __syncthreads();
  if(t==0){
    uint64_t mm=sp.redu[0];
    #pragma unroll
    for(int w8=1;w8<8;w8++) if(sp.redu[w8]>mm) mm=sp.redu[w8];
    sp.redu[0]=mm;
  }
  __syncthreads();
  const int bi = 1023 - (int)(sp.redu[0] & 0xFFFull);
  const float selScore = (float)((int)(sp.redu[0] >> 12)) - 2.0f;
  const bool improve = (selScore > stateF[0]);
  if(!improve) return;

  if(t<9) sp.sModel[t] = models[bi*9+t];
  __syncthreads();

  float U1[PPT],V1[PPT],U2[PPT],V2[PPT];
  #pragma unroll
  for(int q=0;q<PPT;q++){
    int p = t + TPB*q;
    float2 a = ((const float2*)kp1)[p];
    float2 c = ((const float2*)kp2)[p];
    U1[q]=a.x; V1[q]=a.y; U2[q]=c.x; V2[q]=c.y;
  }
  const float s1f=nrm[0], m1xf=nrm[1], m1yf=nrm[2];
  const float s2f=nrm[3], m2xf=nrm[4], m2yf=nrm[5];
  const float tx1=-(s1f*m1xf), ty1=-(s1f*m1yf);
  const float tx2=-(s2f*m2xf), ty2=-(s2f*m2yf);
  const double ns1=(double)s1f, nm1x=(double)m1xf, nm1y=(double)m1yf;
  const double ns2=(double)s2f, nm2x=(double)m2xf, nm2y=(double)m2yf;
  const float epsn = 1e-8f*s2f*s2f;
  const float wk   = 1.0f/(18.0f*s2f);

  uint32_t cm = 0;
  {
    float H[9];
    #pragma unroll
    for(int j=0;j<9;j++) H[j]=sp.sModel[j];
    #pragma unroll
    for(int q=0;q<PPT;q++){
      float e = errsq_f(H, U1[q],V1[q],U2[q],V2[q]);
      cm |= (e <= 2.0f ? 1u : 0u) << q;
    }
  }

  float score = selScore;
  bool active = true;
  float wreg[PPT];

  auto DLT = [&](bool dnorm){
    float part[24];
    #pragma unroll
    for(int kk=0;kk<24;kk++) part[kk]=0.0f;
    #pragma unroll
    for(int q=0;q<PPT;q++){
      float w = wreg[q];
      float x  = fmaf(s1f, U1[q], tx1), y  = fmaf(s1f, V1[q], ty1);
      float x2 = fmaf(s2f, U2[q], tx2), y2 = fmaf(s2f, V2[q], ty2);
      float wx = w*x, wy = w*y;
      float m0=wx*x, m1=wx*y, m2=wy*y;
      float s3 = x2*x2 + y2*y2;
      part[0]+=m0; part[1]+=m1; part[2]+=m2; part[3]+=wx; part[4]+=wy; part[5]+=w;
      part[6]+=x2*m0; part[7]+=x2*m1; part[8]+=x2*m2; part[9]+=x2*wx; part[10]+=x2*wy; part[11]+=x2*w;
      part[12]+=y2*m0; part[13]+=y2*m1; part[14]+=y2*m2; part[15]+=y2*wx; part[16]+=y2*wy; part[17]+=y2*w;
      part[18]+=s3*m0; part[19]+=s3*m1; part[20]+=s3*m2; part[21]+=s3*wx; part[22]+=s3*wy; part[23]+=s3*w;
    }
    float4* rowp = reinterpret_cast<float4*>(&sp.p2b[t][0]);
    rowp[0]=make_float4(part[0],part[1],part[2],part[3]);
    rowp[1]=make_float4(part[4],part[5],part[6],part[7]);
    rowp[2]=make_float4(part[8],part[9],part[10],part[11]);
    rowp[3]=make_float4(part[12],part[13],part[14],part[15]);
    rowp[4]=make_float4(part[16],part[17],part[18],part[19]);
    rowp[5]=make_float4(part[20],part[21],part[22],part[23]);
    __syncthreads();
    if(t<96){
      int qd = t%6, seg = t/6;
      double a0=0,a1=0,a2=0,a3=0;
      #pragma unroll
      for(int rr=0;rr<32;rr++){
        float4 v = *reinterpret_cast<const float4*>(&sp.p2b[seg*32+rr][qd*4]);
        a0+=(double)v.x; a1+=(double)v.y; a2+=(double)v.z; a3+=(double)v.w;
      }
      sp.p3[seg][qd*4+0]=a0; sp.p3[seg][qd*4+1]=a1;
      sp.p3[seg][qd*4+2]=a2; sp.p3[seg][qd*4+3]=a3;
    }
    __syncthreads();
    if(t<24){
      double a=0.0;
      #pragma unroll
      for(int s=0;s<16;s++) a += sp.p3[s][t];
      sp.sMd[t]=a;
    }
    __syncthreads();
    if(t==0) solve24x(sp.sMd, sp.curHn, sp.curH, dnorm, ns1,nm1x,nm1y, ns2,nm2x,nm2y);
    __syncthreads();
  };

  for(int lo=0; lo<5; lo++){
    #pragma unroll
    for(int q=0;q<PPT;q++) wreg[q] = ((cm>>q)&1u) ? 1.0f : 0.0f;
    DLT(false);
    for(int itp=0; itp<4; itp++){
      float Hn[9];
      #pragma unroll
      for(int j=0;j<9;j++) Hn[j]=sp.curHn[j];
      #pragma unroll
      for(int q=0;q<PPT;q++){
        float x  = fmaf(s1f, U1[q], tx1), y  = fmaf(s1f, V1[q], ty1);
        float x2 = fmaf(s2f, U2[q], tx2), y2 = fmaf(s2f, V2[q], ty2);
        float zn = Hn[6]*x + Hn[7]*y + Hn[8];
        float zi = 1.0f/zn;
        float dx = (Hn[0]*x + Hn[1]*y + Hn[2])*zi - x2;
        float dy = (Hn[3]*x + Hn[4]*y + Hn[5])*zi - y2;
        float err = sqrtf(dx*dx + dy*dy + epsn);
        wreg[q] = ((cm>>q)&1u) ? __expf(-err*wk) : 0.0f;
      }
      DLT(itp==3);
    }
    float H[9];
    #pragma unroll
    for(int j=0;j<9;j++) H[j]=sp.curH[j];
    uint32_t nmv = 0;
    #pragma unroll
    for(int q=0;q<PPT;q++){
      float e = errsq_f(H, U1[q],V1[q],U2[q],V2[q]);
      nmv |= (e <= 2.0f ? 1u : 0u) << q;
    }
    int c = __popc(nmv);
    #pragma unroll
    for(int off=32; off>=1; off>>=1) c += __shfl_down(c, off, 64);
    if(lane==0) sp.redi[wv]=c;
    __syncthreads();
    if(t==0){
      int s=0;
      #pragma unroll
      for(int w8=0;w8<8;w8++) s += sp.redi[w8];
      sp.sScore = (float)s;
    }
    __syncthreads();
    float scoreLo = sp.sScore;
    bool better = active && (scoreLo > score);
    if(better){
      if(t<9) sp.sModel[t]=sp.curH[t];
      cm = nmv;
      score = scoreLo;
    }
    active = better;
    __syncthreads();
    if(!active) break;
  }

  // commit
  if(t<9) stateF[2+t] = sp.sModel[t];
  #pragma unroll
  for(int q=0;q<PPT;q++){
    int p = t + TPB*q;
    best_inl[p] = ((cm>>q)&1u) ? 1.0f : 0.0f;
  }
  if(t==0){
    stateF[0] = score;
    float ratio = floorf(score) / 4096.0f;
    float r2 = ratio*ratio, r4 = r2*r2;
    float q  = 1.0f - r4;
    q = fminf(fmaxf(q, 1e-12f), (float)(1.0 - 1e-12));
    float max_samp = (score >= 4096.0f) ? 1.0f : (logf(0.01f)/logf(q));
    stateF[1] = (((float)((pi+1)*NBATCH)) >= floorf(max_samp)) ? 1.0f : 0.0f;
  }
}

// ---------------- init (one 512-thread block) ----------------
__device__ void do_init(ShInit& si, const float* kp1, const float* kp2,
                        float* stateF, float* nrm, float* best_inl){
  const int t = threadIdx.x;
  double s0=0,s1=0,s2=0,s3=0;
  #pragma unroll
  for(int q=0;q<PPT;q++){
    int p = t + TPB*q;
    float2 a = ((const float2*)kp1)[p];
    float2 c = ((const float2*)kp2)[p];
    s0 += (double)a.x; s1 += (double)a.y; s2 += (double)c.x; s3 += (double)c.y;
    best_inl[p] = 0.0f;
  }
  si.arr[t][0]=s0; si.arr[t][1]=s1; si.arr[t][2]=s2; si.arr[t][3]=s3;
  __syncthreads();
  if(t < 4){
    double a = 0;
    for(int r=0;r<TPB;r++) a += si.arr[r][t];
    si.res[t] = a / (double)NPTS;
  }
  __syncthreads();
  const double m1x = si.res[0], m1y = si.res[1];
  const double m2x = si.res[2], m2y = si.res[3];
  __syncthreads();
  double a1=0, a2=0;
  #pragma unroll
  for(int q=0;q<PPT;q++){
    int p = t + TPB*q;
    float2 a = ((const float2*)kp1)[p];
    float2 c = ((const float2*)kp2)[p];
    double dx1=(double)a.x-m1x, dy1=(double)a.y-m1y;
    double dx2=(double)c.x-m2x, dy2=(double)c.y-m2y;
    a1 += sqrt(dx1*dx1+dy1*dy1);
    a2 += sqrt(dx2*dx2+dy2*dy2);
  }
  si.arr[t][0]=a1; si.arr[t][1]=a2;
  __syncthreads();
  if(t < 2){
    double a=0;
    for(int r=0;r<TPB;r++) a += si.arr[r][t];
    si.res[t] = a / (double)NPTS;
  }
  __syncthreads();
  if(t==0){
    double sc1 = si.res[0], sc2 = si.res[1];
    double s1d = 1.4142135623730951/(sc1+1e-8);
    double s2d = 1.4142135623730951/(sc2+1e-8);
    nrm[0]=(float)s1d; nrm[1]=(float)m1x; nrm[2]=(float)m1y;
    nrm[3]=(float)s2d; nrm[4]=(float)m2x; nrm[5]=(float)m2y;
    stateF[0]=4.0f; stateF[1]=0.0f;
    for(int j=0;j<9;j++) stateF[2+j]=0.0f;
  }
}

// ---------------- L_i: sampling(iter i) in blocks 0..1023; block 1024 = init / polish(i-1)
__global__ __launch_bounds__(TPB) void k_iter(int it, uint32_t key0, uint32_t key1,
                                              const float* __restrict__ kp1,
                                              const float* __restrict__ kp2,
                                              float* __restrict__ ws){
  float* stateF   = ws + 0;      // [0]=best_score [1]=done [2..10]=best_model
  float* nrm      = ws + 16;
  float* best_inl = ws + 32;     // 4096
  float* scoresB  = ws + 4128;   // [2][1024]
  float* modelsB  = ws + 6176;   // [2][1024*9]

  const int b = blockIdx.x;
  const int t = threadIdx.x;
  __shared__ ShAll sh;

  if(b == NBATCH){
    // special block: init at it==0, else polish previous iteration
    if(it == 0){
      do_init(sh.i, kp1, kp2, stateF, nrm, best_inl);
    }else{
      const int pi = it - 1;
      do_polish(sh.p, stateF, nrm, scoresB + (pi&1)*NBATCH,
                modelsB + (pi&1)*NBATCH*9, kp1, kp2, best_inl, pi);
    }
    return;
  }

  // -------- sampling block for iteration `it` --------
  if(it > 0){
    // uniform done-gate (polish block may write done concurrently -> broadcast)
    if(t==0) sh.s.sdone = (stateF[1] != 0.0f) ? 1 : 0;
    __syncthreads();
    if(sh.s.sdone) return;
  }
  const int lane = t & 63, wv = t >> 6;
  float* scores = scoresB + (it&1)*NBATCH;
  float* models = modelsB + (it&1)*NBATCH*9;

  uint64_t bb[4] = {0ull,0ull,0ull,0ull};
  #pragma unroll
  for(int j=0;j<8;j++){
    int c = t*8 + j;
    uint32_t f = (uint32_t)(b*NPTS + c);
    uint32_t a0,a1;
    tf2x32(key0,key1, 0u, f, a0,a1);
    uint32_t bits = a0 ^ a1;
    uint64_t v = (uint64_t)((bits>>9) + 1u);
    uint64_t kk = (v<<12) | (uint64_t)(4095 - c);
    ins4(bb, kk);
  }
  sh.s.ls2[0][t]=bb[0]; sh.s.ls2[1][t]=bb[1]; sh.s.ls2[2][t]=bb[2]; sh.s.ls2[3][t]=bb[3];
  __syncthreads();
  for(int off=TPB/2; off>=1; off>>=1){
    if(t < off){
      uint64_t o0=sh.s.ls2[0][t+off], o1=sh.s.ls2[1][t+off];
      uint64_t o2=sh.s.ls2[2][t+off], o3=sh.s.ls2[3][t+off];
      ins4(bb,o0); ins4(bb,o1); ins4(bb,o2); ins4(bb,o3);
      sh.s.ls2[0][t]=bb[0]; sh.s.ls2[1][t]=bb[1]; sh.s.ls2[2][t]=bb[2]; sh.s.ls2[3][t]=bb[3];
    }
    __syncthreads();
  }
  if(t==0){
    double P1[4][2], P2[4][2];
    #pragma unroll
    for(int k=0;k<4;k++){
      int id = 4095 - (int)(bb[k] & 0xFFFull);
      P1[k][0]=(double)kp1[2*id]; P1[k][1]=(double)kp1[2*id+1];
      P2[k][0]=(double)kp2[2*id]; P2[k][1]=(double)kp2[2*id+1];
    }
    float Hf[9]; int fl;
    model4(P1,P2,Hf,&fl);
    #pragma unroll
    for(int j=0;j<9;j++){ models[b*9+j]=Hf[j]; sh.s.sH[j]=Hf[j]; }
    sh.s.sFlag = fl;
  }
  __syncthreads();
  float H[9];
  #pragma unroll
  for(int j=0;j<9;j++) H[j]=sh.s.sH[j];
  int cnt=0;
  #pragma unroll
  for(int j=0;j<PPT;j++){
    int p = t + TPB*j;
    float2 a = ((const float2*)kp1)[p];
    float2 c = ((const float2*)kp2)[p];
    float e = errsq_f(H, a.x, a.y, c.x, c.y);
    cnt += (e <= 2.0f) ? 1 : 0;
  }
  #pragma unroll
  for(int off=32; off>=1; off>>=1) cnt += __shfl_down(cnt, off, 64);
  if(lane==0) sh.s.redi[wv]=cnt;
  __syncthreads();
  if(t==0){
    int s=0;
    #pragma unroll
    for(int w8=0;w8<8;w8++) s += sh.s.redi[w8];
    scores[b] = sh.s.sFlag ? (float)s : -1.0f;
  }
}

// ---------------- final: polish(NIT-1) + writeout ----------------
__global__ __launch_bounds__(TPB) void k_fin(const float* __restrict__ kp1,
                                             const float* __restrict__ kp2,
                                             float* __restrict__ out, int out_size,
                                             float* __restrict__ ws){
  float* stateF   = ws + 0;
  float* nrm      = ws + 16;
  float* best_inl = ws + 32;
  float* scoresB  = ws + 4128;
  float* modelsB  = ws + 6176;
  const int t = threadIdx.x;
  __shared__ ShAll sh;

  const int pi = NIT - 1;
  do_polish(sh.p, stateF, nrm, scoresB + (pi&1)*NBATCH,
            modelsB + (pi&1)*NBATCH*9, kp1, kp2, best_inl, pi);
  __syncthreads();

  if(t<9 && t<out_size) out[t] = stateF[2+t];
  #pragma unroll
  for(int q=0;q<PPT;q++){
    int p = t + TPB*q, o = 9 + p;
    if(o < out_size) out[o] = best_inl[p];
  }
}

// ---------------- host ----------------
extern "C" void kernel_launch(void* const* d_in, const int* in_sizes, int n_in,
                              void* d_out, int out_size, void* d_ws, size_t ws_size,
                              hipStream_t stream) {
  const float* kp1 = (const float*)d_in[0];
  const float* kp2 = (const float*)d_in[1];
  float* out = (float*)d_out;
  float* ws  = (float*)d_ws;

  uint32_t K0h[NIT], K1h[NIT];
  for(int i=0;i<NIT;i++){ uint32_t a,b; tf2x32(0u,42u,0u,(uint32_t)i,a,b); K0h[i]=a; K1h[i]=b; }

  for(int i=0;i<NIT;i++)
    k_iter<<<NBATCH+1, TPB, 0, stream>>>(i, K0h[i], K1h[i], kp1, kp2, ws);
  k_fin<<<1, TPB, 0, stream>>>(kp1, kp2, out, out_size, ws);
}

// Round 10
// 180.179 us; speedup vs baseline: 1.1826x; 1.1826x over previous
//
#include <hip/hip_runtime.h>
#include <cstdint>

#define NPTS   4096
#define NBATCH 1024
#define NIT    10
#define TPB    512
#define PPT    8

// ---------------- threefry2x32 (exact JAX rounds) ----------------
__host__ __device__ inline uint32_t rotl32(uint32_t v, uint32_t r){ return (v<<r)|(v>>(32u-r)); }

__host__ __device__ inline void tf2x32(uint32_t k0,uint32_t k1,uint32_t x0,uint32_t x1,
                                       uint32_t&o0,uint32_t&o1){
  uint32_t ks2 = k0 ^ k1 ^ 0x1BD11BDAu;
  x0 += k0; x1 += k1;
  x0+=x1; x1=rotl32(x1,13); x1^=x0;
  x0+=x1; x1=rotl32(x1,15); x1^=x0;
  x0+=x1; x1=rotl32(x1,26); x1^=x0;
  x0+=x1; x1=rotl32(x1, 6); x1^=x0;
  x0+=k1; x1+=ks2+1u;
  x0+=x1; x1=rotl32(x1,17); x1^=x0;
  x0+=x1; x1=rotl32(x1,29); x1^=x0;
  x0+=x1; x1=rotl32(x1,16); x1^=x0;
  x0+=x1; x1=rotl32(x1,24); x1^=x0;
  x0+=ks2; x1+=k0+2u;
  x0+=x1; x1=rotl32(x1,13); x1^=x0;
  x0+=x1; x1=rotl32(x1,15); x1^=x0;
  x0+=x1; x1=rotl32(x1,26); x1^=x0;
  x0+=x1; x1=rotl32(x1, 6); x1^=x0;
  x0+=k0; x1+=k1+3u;
  x0+=x1; x1=rotl32(x1,17); x1^=x0;
  x0+=x1; x1=rotl32(x1,29); x1^=x0;
  x0+=x1; x1=rotl32(x1,16); x1^=x0;
  x0+=x1; x1=rotl32(x1,24); x1^=x0;
  x0+=k1; x1+=ks2+4u;
  x0+=x1; x1=rotl32(x1,13); x1^=x0;
  x0+=x1; x1=rotl32(x1,15); x1^=x0;
  x0+=x1; x1=rotl32(x1,26); x1^=x0;
  x0+=x1; x1=rotl32(x1, 6); x1^=x0;
  x0+=ks2; x1+=k0+5u;
  o0=x0; o1=x1;
}

// ---------------- math helpers (round-5 verbatim) ----------------
__device__ inline float errsq_f(const float H[9], float x, float y, float kx, float ky){
  float z  = H[6]*x + H[7]*y + H[8];
  float zi = (fabsf(z) > 1e-8f) ? (1.0f/z) : 1.0f;
  float px = (H[0]*x + H[1]*y + H[2])*zi;
  float py = (H[3]*x + H[4]*y + H[5])*zi;
  float dx = px - kx, dy = py - ky;
  return dx*dx + dy*dy;
}

__device__ inline void denorm_h(const double h[9], double s1, double m1x, double m1y,
                                double s2, double m2x, double m2y, float out[9]){
  double G[3][3];
  #pragma unroll
  for(int r=0;r<3;r++){
    double h0=h[3*r], h1=h[3*r+1], h2=h[3*r+2];
    G[r][0] = h0*s1;
    G[r][1] = h1*s1;
    G[r][2] = -s1*m1x*h0 - s1*m1y*h1 + h2;
  }
  double Hm[3][3];
  double inv2 = 1.0/s2;
  #pragma unroll
  for(int c=0;c<3;c++){
    Hm[0][c] = G[0][c]*inv2 + m2x*G[2][c];
    Hm[1][c] = G[1][c]*inv2 + m2y*G[2][c];
    Hm[2][c] = G[2][c];
  }
  double invd = 1.0/(Hm[2][2] + 1e-8);
  #pragma unroll
  for(int r=0;r<3;r++)
    #pragma unroll
    for(int c=0;c<3;c++)
      out[3*r+c] = (float)(Hm[r][c]*invd);
}

__device__ inline double det3c(double ax,double ay, double bx,double by, double cx,double cy){
  return ax*(by-cy) - bx*(ay-cy) + cx*(ay-by);
}

__device__ inline void h4pt(const double P[4][2], double M[3][3]){
  double c0 = det3c(P[3][0],P[3][1], P[1][0],P[1][1], P[2][0],P[2][1]);
  double c1 = det3c(P[0][0],P[0][1], P[3][0],P[3][1], P[2][0],P[2][1]);
  double c2 = det3c(P[0][0],P[0][1], P[1][0],P[1][1], P[3][0],P[3][1]);
  M[0][0]=c0*P[0][0]; M[0][1]=c1*P[1][0]; M[0][2]=c2*P[2][0];
  M[1][0]=c0*P[0][1]; M[1][1]=c1*P[1][1]; M[1][2]=c2*P[2][1];
  M[2][0]=c0;         M[2][1]=c1;         M[2][2]=c2;
}

__device__ inline void adj3(const double M[3][3], double A[3][3]){
  A[0][0]=M[1][1]*M[2][2]-M[1][2]*M[2][1];
  A[0][1]=M[0][2]*M[2][1]-M[0][1]*M[2][2];
  A[0][2]=M[0][1]*M[1][2]-M[0][2]*M[1][1];
  A[1][0]=M[1][2]*M[2][0]-M[1][0]*M[2][2];
  A[1][1]=M[0][0]*M[2][2]-M[0][2]*M[2][0];
  A[1][2]=M[0][2]*M[1][0]-M[0][0]*M[1][2];
  A[2][0]=M[1][0]*M[2][1]-M[1][1]*M[2][0];
  A[2][1]=M[0][1]*M[2][0]-M[0][0]*M[2][1];
  A[2][2]=M[0][0]*M[1][1]-M[0][1]*M[1][0];
}

__device__ inline void chol3(const double A[3][3], double L[3][3], double r[3]){
  double d0 = A[0][0]; if(d0<1e-280) d0=1e-280;
  double l00 = sqrt(d0); double q0 = 1.0/l00;
  double l10 = A[1][0]*q0, l20 = A[2][0]*q0;
  double d1 = A[1][1]-l10*l10; if(d1<1e-280) d1=1e-280;
  double l11 = sqrt(d1); double q1=1.0/l11;
  double l21 = (A[2][1]-l20*l10)*q1;
  double d2 = A[2][2]-l20*l20-l21*l21; if(d2<1e-280) d2=1e-280;
  double l22 = sqrt(d2); double q2=1.0/l22;
  L[0][0]=l00; L[1][0]=l10; L[1][1]=l11; L[2][0]=l20; L[2][1]=l21; L[2][2]=l22;
  r[0]=q0; r[1]=q1; r[2]=q2;
}
__device__ inline void csolve3(const double L[3][3], const double r[3],
                               const double b[3], double x[3]){
  double y0=b[0]*r[0];
  double y1=(b[1]-L[1][0]*y0)*r[1];
  double y2=(b[2]-L[2][0]*y0-L[2][1]*y1)*r[2];
  x[2]=y2*r[2];
  x[1]=(y1-L[2][1]*x[2])*r[1];
  x[0]=(y0-L[1][0]*x[1]-L[2][0]*x[2])*r[0];
}

__device__ inline void ins4(uint64_t b[4], uint64_t k){
  if(k > b[0]){ b[3]=b[2]; b[2]=b[1]; b[1]=b[0]; b[0]=k; }
  else if(k > b[1]){ b[3]=b[2]; b[2]=b[1]; b[1]=k; }
  else if(k > b[2]){ b[3]=b[2]; b[2]=k; }
  else if(k > b[3]){ b[3]=k; }
}

// round-5 solve24 (Cholesky + Schur), verbatim
__device__ inline void solve24(const double* sMd, float curHn[9], float curH[9],
                               bool dnorm, double ns1,double nm1x,double nm1y,
                               double ns2,double nm2x,double nm2y){
  double A0[3][3],A1[3][3],A2[3][3],A3[3][3];
  auto unpackd=[&](const double* s, double M[3][3]){
    M[0][0]=s[0]; M[0][1]=s[1]; M[0][2]=s[3];
    M[1][0]=s[1]; M[1][1]=s[2]; M[1][2]=s[4];
    M[2][0]=s[3]; M[2][1]=s[4]; M[2][2]=s[5];
  };
  unpackd(sMd+0,A0); unpackd(sMd+6,A1); unpackd(sMd+12,A2); unpackd(sMd+18,A3);

  double L0[3][3], q0[3];
  chol3(A0, L0, q0);
  double T1[3][3], T2[3][3];
  #pragma unroll
  for(int c=0;c<3;c++){
    double col[3]={A1[0][c],A1[1][c],A1[2][c]}, x[3];
    csolve3(L0,q0,col,x);
    T1[0][c]=x[0]; T1[1][c]=x[1]; T1[2][c]=x[2];
  }
  #pragma unroll
  for(int c=0;c<3;c++){
    double col[3]={A2[0][c],A2[1][c],A2[2][c]}, x[3];
    csolve3(L0,q0,col,x);
    T2[0][c]=x[0]; T2[1][c]=x[1]; T2[2][c]=x[2];
  }
  double Sc[3][3];
  #pragma unroll
  for(int i=0;i<3;i++)
    #pragma unroll
    for(int j=0;j<3;j++){
      double s = A3[i][j];
      #pragma unroll
      for(int k=0;k<3;k++) s -= A1[i][k]*T1[k][j] + A2[i][k]*T2[k][j];
      Sc[i][j]=s;
    }
  double Ls[3][3], qs[3];
  chol3(Sc, Ls, qs);

  double v[9];
  #pragma unroll
  for(int i=0;i<9;i++) v[i]=1.0;
  #pragma unroll
  for(int itn=0; itn<2; itn++){
    double a[3]={v[0],v[1],v[2]}, bb2[3]={v[3],v[4],v[5]}, cc[3]={v[6],v[7],v[8]};
    double w1[3],w2[3];
    csolve3(L0,q0,a,w1); csolve3(L0,q0,bb2,w2);
    double rhs[3];
    #pragma unroll
    for(int j=0;j<3;j++)
      rhs[j] = cc[j] + T1[0][j]*a[0]+T1[1][j]*a[1]+T1[2][j]*a[2]
                     + T2[0][j]*bb2[0]+T2[1][j]*bb2[1]+T2[2][j]*bb2[2];
    double rr[3];
    csolve3(Ls,qs,rhs,rr);
    #pragma unroll
    for(int i=0;i<3;i++){
      v[i]   = w1[i] + T1[i][0]*rr[0]+T1[i][1]*rr[1]+T1[i][2]*rr[2];
      v[3+i] = w2[i] + T2[i][0]*rr[0]+T2[i][1]*rr[1]+T2[i][2]*rr[2];
      v[6+i] = rr[i];
    }
    if(itn==0){
      double mx=0.0;
      #pragma unroll
      for(int i=0;i<9;i++){ double aa=fabs(v[i]); if(aa>mx) mx=aa; }
      double sc = 1.0/(mx + 1e-300);
      #pragma unroll
      for(int i=0;i<9;i++) v[i]*=sc;
    }
  }
  double n2=0.0;
  #pragma unroll
  for(int i=0;i<9;i++) n2 += v[i]*v[i];
  double invn = 1.0/sqrt(n2);
  #pragma unroll
  for(int i=0;i<9;i++) v[i]*=invn;
  #pragma unroll
  for(int j=0;j<9;j++) curHn[j]=(float)v[j];
  if(dnorm) denorm_h(v, ns1,nm1x,nm1y, ns2,nm2x,nm2y, curH);
}

__device__ inline void model4(const double P1[4][2], const double P2[4][2],
                              float Hf[9], int* flag){
  const int TRI[4][3] = {{0,1,2},{0,1,3},{0,2,3},{1,2,3}};
  bool valid = true;
  #pragma unroll
  for(int tq=0;tq<4;tq++){
    const int i0=TRI[tq][0], i1=TRI[tq][1], i2=TRI[tq][2];
    double d1 = det3c(P1[i0][0],P1[i0][1], P1[i1][0],P1[i1][1], P1[i2][0],P1[i2][1]);
    double d2 = det3c(P2[i0][0],P2[i0][1], P2[i1][0],P2[i1][1], P2[i2][0],P2[i2][1]);
    int s1 = (d1>0.0)-(d1<0.0), s2 = (d2>0.0)-(d2<0.0);
    if(s1 != s2) valid = false;
  }
  double MA[3][3], MB[3][3], AJ[3][3], H[3][3];
  h4pt(P1, MA); h4pt(P2, MB);
  adj3(MA, AJ);
  #pragma unroll
  for(int i=0;i<3;i++)
    #pragma unroll
    for(int j=0;j<3;j++)
      H[i][j] = MB[i][0]*AJ[0][j] + MB[i][1]*AJ[1][j] + MB[i][2]*AJ[2][j];
  double n2=0.0;
  #pragma unroll
  for(int i=0;i<3;i++)
    #pragma unroll
    for(int j=0;j<3;j++) n2 += H[i][j]*H[i][j];
  double invn = 1.0/sqrt(n2);
  double invd = 1.0/(H[2][2]*invn + 1e-8);
  #pragma unroll
  for(int i=0;i<3;i++)
    #pragma unroll
    for(int j=0;j<3;j++) Hf[3*i+j] = (float)(H[i][j]*invn*invd);
  bool diag_ok = (fminf(fminf(fabsf(Hf[0]),fabsf(Hf[4])),fabsf(Hf[8])) > 1e-4f);
  *flag = (valid && diag_ok) ? 1 : 0;
}

// ---------------- shared-memory overlay ----------------
struct ShSample {
  unsigned long long ls2[4][TPB];   // 16 KB, column-major (2-way aliasing, free)
  float sH[9];
  int   sFlag;
  int   redi[8];
  int   sdone;
};
struct ShPolish {                    // = round-5 k_polish LDS, ~69 KB
  float  p2b[TPB][28];
  double p3[16][25];
  double sMd[24];
  unsigned long long redu[8];
  int    redi[8];
  float  sScore;
  float  sModel[9];
  float  curHn[9];
  float  curH[9];
  unsigned char inlb[2][NPTS];
};
struct ShInit {
  double red[TPB];
};
union ShAll { ShSample s; ShPolish p; ShInit i; };

// ---------------- round-5 k_polish body, as a device function ----------------
__device__ void do_polish(ShPolish& sp, float* stateF, const float* nrm,
                          const float* scores, const float* models,
                          const float* kp1, const float* kp2,
                          const float* p1n, const float* p2n,
                          float* best_inl, int iter){
  const int t = threadIdx.x;
  const int lane = t & 63, wv = t >> 6;

  if(stateF[1] != 0.0f) return;

  {
    float sA = scores[t], sB = scores[t+512];
    uint64_t kA = ((uint64_t)(uint32_t)(int)(sA + 2.0f) << 12) | (uint64_t)(1023 - t);
    uint64_t kB = ((uint64_t)(uint32_t)(int)(sB + 2.0f) << 12) | (uint64_t)(1023 - (t+512));
    uint64_t k = (kA >= kB) ? kA : kB;
    #pragma unroll
    for(int off=32; off>=1; off>>=1){
      uint64_t o = __shfl_down(k, off, 64);
      if(o > k) k = o;
    }
    if(lane==0) sp.redu[wv]=k;
  }
  __syncthreads();
  if(t==0){
    uint64_t m=sp.redu[0];
    #pragma unroll
    for(int w8=1;w8<8;w8++) if(sp.redu[w8]>m) m=sp.redu[w8];
    sp.redu[0]=m;
  }
  __syncthreads();
  const int bi = 1023 - (int)(sp.redu[0] & 0xFFFull);
  const float selScore = (float)((int)(sp.redu[0] >> 12)) - 2.0f;

  const float bestScore = stateF[0];
  const bool improve = (selScore > bestScore);
  if(!improve) return;

  if(t<9) sp.sModel[t] = models[bi*9+t];
  __syncthreads();

  float U1[8],V1[8],U2[8],V2[8],X1[8],Y1[8],X2[8],Y2[8];
  #pragma unroll
  for(int q=0;q<8;q++){
    int p = t + 512*q;
    U1[q]=kp1[2*p]; V1[q]=kp1[2*p+1];
    U2[q]=kp2[2*p]; V2[q]=kp2[2*p+1];
    X1[q]=p1n[2*p]; Y1[q]=p1n[2*p+1];
    X2[q]=p2n[2*p]; Y2[q]=p2n[2*p+1];
  }
  {
    float H[9];
    #pragma unroll
    for(int j=0;j<9;j++) H[j]=sp.sModel[j];
    #pragma unroll
    for(int q=0;q<8;q++){
      int p = t + 512*q;
      float e = errsq_f(H, U1[q],V1[q],U2[q],V2[q]);
      sp.inlb[0][p] = (e <= 2.0f) ? 1 : 0;
    }
  }
  __syncthreads();

  int cur = 0;
  float score = selScore;
  bool active = true;
  float wreg[8];

  const double ns1=(double)nrm[0], nm1x=(double)nrm[1], nm1y=(double)nrm[2];
  const double ns2=(double)nrm[3], nm2x=(double)nrm[4], nm2y=(double)nrm[5];
  const float s2f  = nrm[3];
  const float epsn = 1e-8f*s2f*s2f;
  const float wk   = 1.0f/(18.0f*s2f);

  auto DLT = [&](bool denorm_now){
    float part[24];
    #pragma unroll
    for(int k=0;k<24;k++) part[k]=0.0f;
    #pragma unroll
    for(int q=0;q<8;q++){
      float w = wreg[q];
      float x=X1[q], y=Y1[q], x2=X2[q], y2=Y2[q];
      float wx = w*x, wy = w*y;
      float m0=wx*x, m1=wx*y, m2=wy*y;
      float s3 = x2*x2 + y2*y2;
      part[0]+=m0; part[1]+=m1; part[2]+=m2; part[3]+=wx; part[4]+=wy; part[5]+=w;
      part[6]+=x2*m0; part[7]+=x2*m1; part[8]+=x2*m2; part[9]+=x2*wx; part[10]+=x2*wy; part[11]+=x2*w;
      part[12]+=y2*m0; part[13]+=y2*m1; part[14]+=y2*m2; part[15]+=y2*wx; part[16]+=y2*wy; part[17]+=y2*w;
      part[18]+=s3*m0; part[19]+=s3*m1; part[20]+=s3*m2; part[21]+=s3*wx; part[22]+=s3*wy; part[23]+=s3*w;
    }
    float4* rowp = reinterpret_cast<float4*>(&sp.p2b[t][0]);
    rowp[0]=make_float4(part[0],part[1],part[2],part[3]);
    rowp[1]=make_float4(part[4],part[5],part[6],part[7]);
    rowp[2]=make_float4(part[8],part[9],part[10],part[11]);
    rowp[3]=make_float4(part[12],part[13],part[14],part[15]);
    rowp[4]=make_float4(part[16],part[17],part[18],part[19]);
    rowp[5]=make_float4(part[20],part[21],part[22],part[23]);
    __syncthreads();
    if(t<96){
      int qd = t%6, seg = t/6;
      double a0=0,a1=0,a2=0,a3=0;
      #pragma unroll
      for(int i=0;i<32;i++){
        float4 v = *reinterpret_cast<const float4*>(&sp.p2b[seg*32+i][qd*4]);
        a0+=(double)v.x; a1+=(double)v.y; a2+=(double)v.z; a3+=(double)v.w;
      }
      sp.p3[seg][qd*4+0]=a0; sp.p3[seg][qd*4+1]=a1;
      sp.p3[seg][qd*4+2]=a2; sp.p3[seg][qd*4+3]=a3;
    }
    __syncthreads();
    if(t<24){
      double a=0.0;
      #pragma unroll
      for(int s=0;s<16;s++) a += sp.p3[s][t];
      sp.sMd[t]=a;
    }
    __syncthreads();
    if(t==0) solve24(sp.sMd, sp.curHn, sp.curH, denorm_now, ns1,nm1x,nm1y, ns2,nm2x,nm2y);
    __syncthreads();
  };

  for(int lo=0; lo<5; lo++){
    #pragma unroll
    for(int q=0;q<8;q++){ int p=t+512*q; wreg[q] = sp.inlb[cur][p] ? 1.0f : 0.0f; }
    DLT(false);
    for(int itp=0; itp<4; itp++){
      float Hn[9];
      #pragma unroll
      for(int j=0;j<9;j++) Hn[j]=sp.curHn[j];
      #pragma unroll
      for(int q=0;q<8;q++){
        int p=t+512*q;
        float zn = Hn[6]*X1[q] + Hn[7]*Y1[q] + Hn[8];
        float zi = 1.0f/zn;
        float dx = (Hn[0]*X1[q] + Hn[1]*Y1[q] + Hn[2])*zi - X2[q];
        float dy = (Hn[3]*X1[q] + Hn[4]*Y1[q] + Hn[5])*zi - Y2[q];
        float err = sqrtf(dx*dx + dy*dy + epsn);
        wreg[q] = sp.inlb[cur][p] ? __expf(-err*wk) : 0.0f;
      }
      DLT(itp==3);
    }
    float scoreLo;
    {
      float H[9];
      #pragma unroll
      for(int j=0;j<9;j++) H[j]=sp.curH[j];
      int c=0;
      #pragma unroll
      for(int q=0;q<8;q++){
        int p=t+512*q;
        float e = errsq_f(H, U1[q],V1[q],U2[q],V2[q]);
        unsigned char bb = (e <= 2.0f) ? 1 : 0;
        sp.inlb[cur^1][p] = bb;
        c += bb;
      }
      #pragma unroll
      for(int off=32; off>=1; off>>=1) c += __shfl_down(c, off, 64);
      if(lane==0) sp.redi[wv]=c;
      __syncthreads();
      if(t==0){
        int s=0;
        #pragma unroll
        for(int w8=0;w8<8;w8++) s += sp.redi[w8];
        sp.sScore=(float)s;
      }
      __syncthreads();
      scoreLo = sp.sScore;
    }
    bool better = active && (scoreLo > score);
    if(better){
      if(t<9) sp.sModel[t]=sp.curH[t];
      cur ^= 1;
      score = scoreLo;
    }
    active = better;
    __syncthreads();
    if(!active) break;
  }

  if(t<9) stateF[2+t] = sp.sModel[t];
  #pragma unroll
  for(int q=0;q<8;q++){ int p=t+512*q; best_inl[p] = sp.inlb[cur][p] ? 1.0f : 0.0f; }
  if(t==0){
    stateF[0] = score;
    float ratio = floorf(score) / 4096.0f;
    float r2 = ratio*ratio, r4 = r2*r2;
    float q  = 1.0f - r4;
    q = fminf(fmaxf(q, 1e-12f), (float)(1.0 - 1e-12));
    float max_samp = (score >= 4096.0f) ? 1.0f : (logf(0.01f)/logf(q));
    stateF[1] = (((float)((iter+1)*NBATCH)) >= floorf(max_samp)) ? 1.0f : 0.0f;
  }
}

// ---------------- init (round-5 math, 512 threads) ----------------
__device__ void do_init(ShInit& si, const float* kp1, const float* kp2,
                        float* stateF, float* nrm, float* best_inl,
                        float* p1n, float* p2n){
  const int t = threadIdx.x;
  auto blk_reduce = [&](double v)->double{
    si.red[t]=v; __syncthreads();
    for(int off=256; off>=1; off>>=1){ if(t<off) si.red[t]+=si.red[t+off]; __syncthreads(); }
    double rr = si.red[0]; __syncthreads(); return rr;
  };
  double sx1=0, sy1=0, sx2=0, sy2=0;
  #pragma unroll
  for(int q=0;q<8;q++){
    int p = t + 512*q;
    sx1 += (double)kp1[2*p];   sy1 += (double)kp1[2*p+1];
    sx2 += (double)kp2[2*p];   sy2 += (double)kp2[2*p+1];
  }
  double m1x = blk_reduce(sx1)/(double)NPTS;
  double m1y = blk_reduce(sy1)/(double)NPTS;
  double m2x = blk_reduce(sx2)/(double)NPTS;
  double m2y = blk_reduce(sy2)/(double)NPTS;
  double a1=0, a2=0;
  #pragma unroll
  for(int q=0;q<8;q++){
    int p = t + 512*q;
    double dx1=(double)kp1[2*p]-m1x, dy1=(double)kp1[2*p+1]-m1y;
    double dx2=(double)kp2[2*p]-m2x, dy2=(double)kp2[2*p+1]-m2y;
    a1 += sqrt(dx1*dx1+dy1*dy1);
    a2 += sqrt(dx2*dx2+dy2*dy2);
  }
  double sc1 = blk_reduce(a1)/(double)NPTS;
  double sc2 = blk_reduce(a2)/(double)NPTS;
  double s1 = 1.4142135623730951/(sc1+1e-8);
  double s2 = 1.4142135623730951/(sc2+1e-8);
  if(t==0){
    nrm[0]=(float)s1; nrm[1]=(float)m1x; nrm[2]=(float)m1y;
    nrm[3]=(float)s2; nrm[4]=(float)m2x; nrm[5]=(float)m2y;
    stateF[0]=4.0f; stateF[1]=0.0f;
    for(int j=0;j<9;j++) stateF[2+j]=0.0f;
  }
  #pragma unroll
  for(int q=0;q<8;q++){
    int p = t + 512*q;
    p1n[2*p]   = (float)(s1*((double)kp1[2*p]  -m1x));
    p1n[2*p+1] = (float)(s1*((double)kp1[2*p+1]-m1y));
    p2n[2*p]   = (float)(s2*((double)kp2[2*p]  -m2x));
    p2n[2*p+1] = (float)(s2*((double)kp2[2*p+1]-m2y));
    best_inl[p] = 0.0f;
  }
}

// ---------------- L_it: block 0 = init(it==0) / polish(it-1); blocks 1..1024 = sampling(it)
__global__ __launch_bounds__(TPB) void k_iter(int it, uint32_t key0, uint32_t key1,
                                              const float* __restrict__ kp1,
                                              const float* __restrict__ kp2,
                                              float* __restrict__ ws){
  float* stateF   = ws + 0;      // [0]=best_score [1]=done [2..10]=best_model
  float* nrm      = ws + 16;
  float* best_inl = ws + 32;     // 4096
  float* p1n      = ws + 4128;   // 8192
  float* p2n      = ws + 12320;  // 8192
  float* scoresB  = ws + 20512;  // [2][1024]
  float* modelsB  = ws + 22560;  // [2][1024*9]

  const int b = blockIdx.x;
  const int t = threadIdx.x;
  __shared__ ShAll sh;

  if(b == 0){
    if(it == 0){
      do_init(sh.i, kp1, kp2, stateF, nrm, best_inl, p1n, p2n);
    }else{
      const int pi = it - 1;
      do_polish(sh.p, stateF, nrm, scoresB + (pi&1)*NBATCH,
                modelsB + (pi&1)*NBATCH*9, kp1, kp2, p1n, p2n, best_inl, pi);
    }
    return;
  }

  // -------- sampling block, row r = b-1 --------
  const int r = b - 1;
  if(it > 0){
    if(t==0) sh.s.sdone = (stateF[1] != 0.0f) ? 1 : 0;
    __syncthreads();
    if(sh.s.sdone) return;
  }
  const int lane = t & 63, wv = t >> 6;
  float* scores = scoresB + (it&1)*NBATCH;
  float* models = modelsB + (it&1)*NBATCH*9;

  uint64_t bb[4] = {0ull,0ull,0ull,0ull};
  #pragma unroll
  for(int j=0;j<8;j++){
    int c = t*8 + j;
    uint32_t f = (uint32_t)(r*NPTS + c);
    uint32_t a0,a1;
    tf2x32(key0,key1, 0u, f, a0,a1);
    uint32_t bits = a0 ^ a1;
    uint64_t v = (uint64_t)((bits>>9) + 1u);
    uint64_t kk = (v<<12) | (uint64_t)(4095 - c);
    ins4(bb, kk);
  }
  sh.s.ls2[0][t]=bb[0]; sh.s.ls2[1][t]=bb[1]; sh.s.ls2[2][t]=bb[2]; sh.s.ls2[3][t]=bb[3];
  __syncthreads();
  for(int off=TPB/2; off>=1; off>>=1){
    if(t < off){
      uint64_t o0=sh.s.ls2[0][t+off], o1=sh.s.ls2[1][t+off];
      uint64_t o2=sh.s.ls2[2][t+off], o3=sh.s.ls2[3][t+off];
      ins4(bb,o0); ins4(bb,o1); ins4(bb,o2); ins4(bb,o3);
      sh.s.ls2[0][t]=bb[0]; sh.s.ls2[1][t]=bb[1]; sh.s.ls2[2][t]=bb[2]; sh.s.ls2[3][t]=bb[3];
    }
    __syncthreads();
  }
  if(t==0){
    double P1[4][2], P2[4][2];
    #pragma unroll
    for(int k=0;k<4;k++){
      int id = 4095 - (int)(bb[k] & 0xFFFull);
      P1[k][0]=(double)kp1[2*id]; P1[k][1]=(double)kp1[2*id+1];
      P2[k][0]=(double)kp2[2*id]; P2[k][1]=(double)kp2[2*id+1];
    }
    float Hf[9]; int fl;
    model4(P1,P2,Hf,&fl);
    #pragma unroll
    for(int j=0;j<9;j++){ models[r*9+j]=Hf[j]; sh.s.sH[j]=Hf[j]; }
    sh.s.sFlag = fl;
  }
  __syncthreads();
  float H[9];
  #pragma unroll
  for(int j=0;j<9;j++) H[j]=sh.s.sH[j];
  int cnt=0;
  #pragma unroll
  for(int j=0;j<PPT;j++){
    int p = t + TPB*j;
    float2 a = ((const float2*)kp1)[p];
    float2 c = ((const float2*)kp2)[p];
    float e = errsq_f(H, a.x, a.y, c.x, c.y);
    cnt += (e <= 2.0f) ? 1 : 0;
  }
  #pragma unroll
  for(int off=32; off>=1; off>>=1) cnt += __shfl_down(cnt, off, 64);
  if(lane==0) sh.s.redi[wv]=cnt;
  __syncthreads();
  if(t==0){
    int s=0;
    #pragma unroll
    for(int w8=0;w8<8;w8++) s += sh.s.redi[w8];
    scores[r] = sh.s.sFlag ? (float)s : -1.0f;
  }
}

// ---------------- final: polish(NIT-1) + writeout ----------------
__global__ __launch_bounds__(TPB) void k_fin(const float* __restrict__ kp1,
                                             const float* __restrict__ kp2,
                                             float* __restrict__ out, int out_size,
                                             float* __restrict__ ws){
  float* stateF   = ws + 0;
  float* nrm      = ws + 16;
  float* best_inl = ws + 32;
  float* p1n      = ws + 4128;
  float* p2n      = ws + 12320;
  float* scoresB  = ws + 20512;
  float* modelsB  = ws + 22560;
  const int t = threadIdx.x;
  __shared__ ShAll sh;

  const int pi = NIT - 1;
  do_polish(sh.p, stateF, nrm, scoresB + (pi&1)*NBATCH,
            modelsB + (pi&1)*NBATCH*9, kp1, kp2, p1n, p2n, best_inl, pi);
  __syncthreads();

  if(t<9 && t<out_size) out[t] = stateF[2+t];
  #pragma unroll
  for(int q=0;q<PPT;q++){
    int p = t + TPB*q, o = 9 + p;
    if(o < out_size) out[o] = best_inl[p];
  }
}

// ---------------- host ----------------
extern "C" void kernel_launch(void* const* d_in, const int* in_sizes, int n_in,
                              void* d_out, int out_size, void* d_ws, size_t ws_size,
                              hipStream_t stream) {
  const float* kp1 = (const float*)d_in[0];
  const float* kp2 = (const float*)d_in[1];
  float* out = (float*)d_out;
  float* ws  = (float*)d_ws;

  uint32_t K0h[NIT], K1h[NIT];
  for(int i=0;i<NIT;i++){ uint32_t a,b; tf2x32(0u,42u,0u,(uint32_t)i,a,b); K0h[i]=a; K1h[i]=b; }

  for(int i=0;i<NIT;i++)
    k_iter<<<NBATCH+1, TPB, 0, stream>>>(i, K0h[i], K1h[i], kp1, kp2, ws);
  k_fin<<<1, TPB, 0, stream>>>(kp1, kp2, out, out_size, ws);
}

// Round 11
// 179.456 us; speedup vs baseline: 1.1873x; 1.0040x over previous
//
#include <hip/hip_runtime.h>
#include <cstdint>

#define NPTS   4096
#define NBATCH 1024
#define NIT    10
#define TPB    512
#define PPT    8

// ---------------- threefry2x32 (exact JAX rounds) ----------------
__host__ __device__ inline uint32_t rotl32(uint32_t v, uint32_t r){ return (v<<r)|(v>>(32u-r)); }

__host__ __device__ inline void tf2x32(uint32_t k0,uint32_t k1,uint32_t x0,uint32_t x1,
                                       uint32_t&o0,uint32_t&o1){
  uint32_t ks2 = k0 ^ k1 ^ 0x1BD11BDAu;
  x0 += k0; x1 += k1;
  x0+=x1; x1=rotl32(x1,13); x1^=x0;
  x0+=x1; x1=rotl32(x1,15); x1^=x0;
  x0+=x1; x1=rotl32(x1,26); x1^=x0;
  x0+=x1; x1=rotl32(x1, 6); x1^=x0;
  x0+=k1; x1+=ks2+1u;
  x0+=x1; x1=rotl32(x1,17); x1^=x0;
  x0+=x1; x1=rotl32(x1,29); x1^=x0;
  x0+=x1; x1=rotl32(x1,16); x1^=x0;
  x0+=x1; x1=rotl32(x1,24); x1^=x0;
  x0+=ks2; x1+=k0+2u;
  x0+=x1; x1=rotl32(x1,13); x1^=x0;
  x0+=x1; x1=rotl32(x1,15); x1^=x0;
  x0+=x1; x1=rotl32(x1,26); x1^=x0;
  x0+=x1; x1=rotl32(x1, 6); x1^=x0;
  x0+=k0; x1+=k1+3u;
  x0+=x1; x1=rotl32(x1,17); x1^=x0;
  x0+=x1; x1=rotl32(x1,29); x1^=x0;
  x0+=x1; x1=rotl32(x1,16); x1^=x0;
  x0+=x1; x1=rotl32(x1,24); x1^=x0;
  x0+=k1; x1+=ks2+4u;
  x0+=x1; x1=rotl32(x1,13); x1^=x0;
  x0+=x1; x1=rotl32(x1,15); x1^=x0;
  x0+=x1; x1=rotl32(x1,26); x1^=x0;
  x0+=x1; x1=rotl32(x1, 6); x1^=x0;
  x0+=ks2; x1+=k0+5u;
  o0=x0; o1=x1;
}

// ---------------- math helpers (round-5 verbatim) ----------------
__device__ inline float errsq_f(const float H[9], float x, float y, float kx, float ky){
  float z  = H[6]*x + H[7]*y + H[8];
  float zi = (fabsf(z) > 1e-8f) ? (1.0f/z) : 1.0f;
  float px = (H[0]*x + H[1]*y + H[2])*zi;
  float py = (H[3]*x + H[4]*y + H[5])*zi;
  float dx = px - kx, dy = py - ky;
  return dx*dx + dy*dy;
}

__device__ inline void denorm_h(const double h[9], double s1, double m1x, double m1y,
                                double s2, double m2x, double m2y, float out[9]){
  double G[3][3];
  #pragma unroll
  for(int r=0;r<3;r++){
    double h0=h[3*r], h1=h[3*r+1], h2=h[3*r+2];
    G[r][0] = h0*s1;
    G[r][1] = h1*s1;
    G[r][2] = -s1*m1x*h0 - s1*m1y*h1 + h2;
  }
  double Hm[3][3];
  double inv2 = 1.0/s2;
  #pragma unroll
  for(int c=0;c<3;c++){
    Hm[0][c] = G[0][c]*inv2 + m2x*G[2][c];
    Hm[1][c] = G[1][c]*inv2 + m2y*G[2][c];
    Hm[2][c] = G[2][c];
  }
  double invd = 1.0/(Hm[2][2] + 1e-8);
  #pragma unroll
  for(int r=0;r<3;r++)
    #pragma unroll
    for(int c=0;c<3;c++)
      out[3*r+c] = (float)(Hm[r][c]*invd);
}

__device__ inline double det3c(double ax,double ay, double bx,double by, double cx,double cy){
  return ax*(by-cy) - bx*(ay-cy) + cx*(ay-by);
}

__device__ inline void h4pt(const double P[4][2], double M[3][3]){
  double c0 = det3c(P[3][0],P[3][1], P[1][0],P[1][1], P[2][0],P[2][1]);
  double c1 = det3c(P[0][0],P[0][1], P[3][0],P[3][1], P[2][0],P[2][1]);
  double c2 = det3c(P[0][0],P[0][1], P[1][0],P[1][1], P[3][0],P[3][1]);
  M[0][0]=c0*P[0][0]; M[0][1]=c1*P[1][0]; M[0][2]=c2*P[2][0];
  M[1][0]=c0*P[0][1]; M[1][1]=c1*P[1][1]; M[1][2]=c2*P[2][1];
  M[2][0]=c0;         M[2][1]=c1;         M[2][2]=c2;
}

__device__ inline void adj3(const double M[3][3], double A[3][3]){
  A[0][0]=M[1][1]*M[2][2]-M[1][2]*M[2][1];
  A[0][1]=M[0][2]*M[2][1]-M[0][1]*M[2][2];
  A[0][2]=M[0][1]*M[1][2]-M[0][2]*M[1][1];
  A[1][0]=M[1][2]*M[2][0]-M[1][0]*M[2][2];
  A[1][1]=M[0][0]*M[2][2]-M[0][2]*M[2][0];
  A[1][2]=M[0][2]*M[1][0]-M[0][0]*M[1][2];
  A[2][0]=M[1][0]*M[2][1]-M[1][1]*M[2][0];
  A[2][1]=M[0][1]*M[2][0]-M[0][0]*M[2][1];
  A[2][2]=M[0][0]*M[1][1]-M[0][1]*M[1][0];
}

__device__ inline void chol3(const double A[3][3], double L[3][3], double r[3]){
  double d0 = A[0][0]; if(d0<1e-280) d0=1e-280;
  double l00 = sqrt(d0); double q0 = 1.0/l00;
  double l10 = A[1][0]*q0, l20 = A[2][0]*q0;
  double d1 = A[1][1]-l10*l10; if(d1<1e-280) d1=1e-280;
  double l11 = sqrt(d1); double q1=1.0/l11;
  double l21 = (A[2][1]-l20*l10)*q1;
  double d2 = A[2][2]-l20*l20-l21*l21; if(d2<1e-280) d2=1e-280;
  double l22 = sqrt(d2); double q2=1.0/l22;
  L[0][0]=l00; L[1][0]=l10; L[1][1]=l11; L[2][0]=l20; L[2][1]=l21; L[2][2]=l22;
  r[0]=q0; r[1]=q1; r[2]=q2;
}
__device__ inline void csolve3(const double L[3][3], const double r[3],
                               const double b[3], double x[3]){
  double y0=b[0]*r[0];
  double y1=(b[1]-L[1][0]*y0)*r[1];
  double y2=(b[2]-L[2][0]*y0-L[2][1]*y1)*r[2];
  x[2]=y2*r[2];
  x[1]=(y1-L[2][1]*x[2])*r[1];
  x[0]=(y0-L[1][0]*x[1]-L[2][0]*x[2])*r[0];
}

__device__ inline void ins4(uint64_t b[4], uint64_t k){
  if(k > b[0]){ b[3]=b[2]; b[2]=b[1]; b[1]=b[0]; b[0]=k; }
  else if(k > b[1]){ b[3]=b[2]; b[2]=b[1]; b[1]=k; }
  else if(k > b[2]){ b[3]=b[2]; b[2]=k; }
  else if(k > b[3]){ b[3]=k; }
}

// round-5 solve24 (Cholesky + Schur), verbatim
__device__ inline void solve24(const double* sMd, float curHn[9], float curH[9],
                               bool dnorm, double ns1,double nm1x,double nm1y,
                               double ns2,double nm2x,double nm2y){
  double A0[3][3],A1[3][3],A2[3][3],A3[3][3];
  auto unpackd=[&](const double* s, double M[3][3]){
    M[0][0]=s[0]; M[0][1]=s[1]; M[0][2]=s[3];
    M[1][0]=s[1]; M[1][1]=s[2]; M[1][2]=s[4];
    M[2][0]=s[3]; M[2][1]=s[4]; M[2][2]=s[5];
  };
  unpackd(sMd+0,A0); unpackd(sMd+6,A1); unpackd(sMd+12,A2); unpackd(sMd+18,A3);

  double L0[3][3], q0[3];
  chol3(A0, L0, q0);
  double T1[3][3], T2[3][3];
  #pragma unroll
  for(int c=0;c<3;c++){
    double col[3]={A1[0][c],A1[1][c],A1[2][c]}, x[3];
    csolve3(L0,q0,col,x);
    T1[0][c]=x[0]; T1[1][c]=x[1]; T1[2][c]=x[2];
  }
  #pragma unroll
  for(int c=0;c<3;c++){
    double col[3]={A2[0][c],A2[1][c],A2[2][c]}, x[3];
    csolve3(L0,q0,col,x);
    T2[0][c]=x[0]; T2[1][c]=x[1]; T2[2][c]=x[2];
  }
  double Sc[3][3];
  #pragma unroll
  for(int i=0;i<3;i++)
    #pragma unroll
    for(int j=0;j<3;j++){
      double s = A3[i][j];
      #pragma unroll
      for(int k=0;k<3;k++) s -= A1[i][k]*T1[k][j] + A2[i][k]*T2[k][j];
      Sc[i][j]=s;
    }
  double Ls[3][3], qs[3];
  chol3(Sc, Ls, qs);

  double v[9];
  #pragma unroll
  for(int i=0;i<9;i++) v[i]=1.0;
  #pragma unroll
  for(int itn=0; itn<2; itn++){
    double a[3]={v[0],v[1],v[2]}, bb2[3]={v[3],v[4],v[5]}, cc[3]={v[6],v[7],v[8]};
    double w1[3],w2[3];
    csolve3(L0,q0,a,w1); csolve3(L0,q0,bb2,w2);
    double rhs[3];
    #pragma unroll
    for(int j=0;j<3;j++)
      rhs[j] = cc[j] + T1[0][j]*a[0]+T1[1][j]*a[1]+T1[2][j]*a[2]
                     + T2[0][j]*bb2[0]+T2[1][j]*bb2[1]+T2[2][j]*bb2[2];
    double rr[3];
    csolve3(Ls,qs,rhs,rr);
    #pragma unroll
    for(int i=0;i<3;i++){
      v[i]   = w1[i] + T1[i][0]*rr[0]+T1[i][1]*rr[1]+T1[i][2]*rr[2];
      v[3+i] = w2[i] + T2[i][0]*rr[0]+T2[i][1]*rr[1]+T2[i][2]*rr[2];
      v[6+i] = rr[i];
    }
    if(itn==0){
      double mx=0.0;
      #pragma unroll
      for(int i=0;i<9;i++){ double aa=fabs(v[i]); if(aa>mx) mx=aa; }
      double sc = 1.0/(mx + 1e-300);
      #pragma unroll
      for(int i=0;i<9;i++) v[i]*=sc;
    }
  }
  double n2=0.0;
  #pragma unroll
  for(int i=0;i<9;i++) n2 += v[i]*v[i];
  double invn = 1.0/sqrt(n2);
  #pragma unroll
  for(int i=0;i<9;i++) v[i]*=invn;
  #pragma unroll
  for(int j=0;j<9;j++) curHn[j]=(float)v[j];
  if(dnorm) denorm_h(v, ns1,nm1x,nm1y, ns2,nm2x,nm2y, curH);
}

__device__ inline void model4(const double P1[4][2], const double P2[4][2],
                              float Hf[9], int* flag){
  const int TRI[4][3] = {{0,1,2},{0,1,3},{0,2,3},{1,2,3}};
  bool valid = true;
  #pragma unroll
  for(int tq=0;tq<4;tq++){
    const int i0=TRI[tq][0], i1=TRI[tq][1], i2=TRI[tq][2];
    double d1 = det3c(P1[i0][0],P1[i0][1], P1[i1][0],P1[i1][1], P1[i2][0],P1[i2][1]);
    double d2 = det3c(P2[i0][0],P2[i0][1], P2[i1][0],P2[i1][1], P2[i2][0],P2[i2][1]);
    int s1 = (d1>0.0)-(d1<0.0), s2 = (d2>0.0)-(d2<0.0);
    if(s1 != s2) valid = false;
  }
  double MA[3][3], MB[3][3], AJ[3][3], H[3][3];
  h4pt(P1, MA); h4pt(P2, MB);
  adj3(MA, AJ);
  #pragma unroll
  for(int i=0;i<3;i++)
    #pragma unroll
    for(int j=0;j<3;j++)
      H[i][j] = MB[i][0]*AJ[0][j] + MB[i][1]*AJ[1][j] + MB[i][2]*AJ[2][j];
  double n2=0.0;
  #pragma unroll
  for(int i=0;i<3;i++)
    #pragma unroll
    for(int j=0;j<3;j++) n2 += H[i][j]*H[i][j];
  double invn = 1.0/sqrt(n2);
  double invd = 1.0/(H[2][2]*invn + 1e-8);
  #pragma unroll
  for(int i=0;i<3;i++)
    #pragma unroll
    for(int j=0;j<3;j++) Hf[3*i+j] = (float)(H[i][j]*invn*invd);
  bool diag_ok = (fminf(fminf(fabsf(Hf[0]),fabsf(Hf[4])),fabsf(Hf[8])) > 1e-4f);
  *flag = (valid && diag_ok) ? 1 : 0;
}

// ---------------- shared-memory overlay ----------------
struct ShSample {
  unsigned long long ls2[4][TPB];   // 16 KB, column-major (2-way aliasing, free)
  float sH[9];
  int   sFlag;
  int   redi[8];
  int   sdone;
};
struct ShPolish {                    // = round-5 k_polish LDS, ~69 KB
  float  p2b[TPB][28];
  double p3[16][25];
  double sMd[24];
  unsigned long long redu[8];
  int    redi[8];
  float  sScore;
  float  sModel[9];
  float  curHn[9];
  float  curH[9];
  unsigned char inlb[2][NPTS];
};
struct ShInit {
  double red[TPB];
};
// Occupancy control: force LDS/block > 80 KB so only ONE block per CU is
// resident. The polish block then owns its CU exclusively — round-10's PMC
// showed embedded polish at 95-105 us vs 61 standalone, attributed to
// co-resident sampling waves stealing VALU issue slots (2 blocks/CU at 69KB).
struct ShPad { char x[81960]; };
union ShAll { ShSample s; ShPolish p; ShInit i; ShPad pad; };

// ---------------- round-5 k_polish body, as a device function ----------------
__device__ void do_polish(ShPolish& sp, float* stateF, const float* nrm,
                          const float* scores, const float* models,
                          const float* kp1, const float* kp2,
                          const float* p1n, const float* p2n,
                          float* best_inl, int iter){
  const int t = threadIdx.x;
  const int lane = t & 63, wv = t >> 6;

  if(stateF[1] != 0.0f) return;

  {
    float sA = scores[t], sB = scores[t+512];
    uint64_t kA = ((uint64_t)(uint32_t)(int)(sA + 2.0f) << 12) | (uint64_t)(1023 - t);
    uint64_t kB = ((uint64_t)(uint32_t)(int)(sB + 2.0f) << 12) | (uint64_t)(1023 - (t+512));
    uint64_t k = (kA >= kB) ? kA : kB;
    #pragma unroll
    for(int off=32; off>=1; off>>=1){
      uint64_t o = __shfl_down(k, off, 64);
      if(o > k) k = o;
    }
    if(lane==0) sp.redu[wv]=k;
  }
  __syncthreads();
  if(t==0){
    uint64_t m=sp.redu[0];
    #pragma unroll
    for(int w8=1;w8<8;w8++) if(sp.redu[w8]>m) m=sp.redu[w8];
    sp.redu[0]=m;
  }
  __syncthreads();
  const int bi = 1023 - (int)(sp.redu[0] & 0xFFFull);
  const float selScore = (float)((int)(sp.redu[0] >> 12)) - 2.0f;

  const float bestScore = stateF[0];
  const bool improve = (selScore > bestScore);
  if(!improve) return;

  if(t<9) sp.sModel[t] = models[bi*9+t];
  __syncthreads();

  float U1[8],V1[8],U2[8],V2[8],X1[8],Y1[8],X2[8],Y2[8];
  #pragma unroll
  for(int q=0;q<8;q++){
    int p = t + 512*q;
    U1[q]=kp1[2*p]; V1[q]=kp1[2*p+1];
    U2[q]=kp2[2*p]; V2[q]=kp2[2*p+1];
    X1[q]=p1n[2*p]; Y1[q]=p1n[2*p+1];
    X2[q]=p2n[2*p]; Y2[q]=p2n[2*p+1];
  }
  {
    float H[9];
    #pragma unroll
    for(int j=0;j<9;j++) H[j]=sp.sModel[j];
    #pragma unroll
    for(int q=0;q<8;q++){
      int p = t + 512*q;
      float e = errsq_f(H, U1[q],V1[q],U2[q],V2[q]);
      sp.inlb[0][p] = (e <= 2.0f) ? 1 : 0;
    }
  }
  __syncthreads();

  int cur = 0;
  float score = selScore;
  bool active = true;
  float wreg[8];

  const double ns1=(double)nrm[0], nm1x=(double)nrm[1], nm1y=(double)nrm[2];
  const double ns2=(double)nrm[3], nm2x=(double)nrm[4], nm2y=(double)nrm[5];
  const float s2f  = nrm[3];
  const float epsn = 1e-8f*s2f*s2f;
  const float wk   = 1.0f/(18.0f*s2f);

  auto DLT = [&](bool denorm_now){
    float part[24];
    #pragma unroll
    for(int k=0;k<24;k++) part[k]=0.0f;
    #pragma unroll
    for(int q=0;q<8;q++){
      float w = wreg[q];
      float x=X1[q], y=Y1[q], x2=X2[q], y2=Y2[q];
      float wx = w*x, wy = w*y;
      float m0=wx*x, m1=wx*y, m2=wy*y;
      float s3 = x2*x2 + y2*y2;
      part[0]+=m0; part[1]+=m1; part[2]+=m2; part[3]+=wx; part[4]+=wy; part[5]+=w;
      part[6]+=x2*m0; part[7]+=x2*m1; part[8]+=x2*m2; part[9]+=x2*wx; part[10]+=x2*wy; part[11]+=x2*w;
      part[12]+=y2*m0; part[13]+=y2*m1; part[14]+=y2*m2; part[15]+=y2*wx; part[16]+=y2*wy; part[17]+=y2*w;
      part[18]+=s3*m0; part[19]+=s3*m1; part[20]+=s3*m2; part[21]+=s3*wx; part[22]+=s3*wy; part[23]+=s3*w;
    }
    float4* rowp = reinterpret_cast<float4*>(&sp.p2b[t][0]);
    rowp[0]=make_float4(part[0],part[1],part[2],part[3]);
    rowp[1]=make_float4(part[4],part[5],part[6],part[7]);
    rowp[2]=make_float4(part[8],part[9],part[10],part[11]);
    rowp[3]=make_float4(part[12],part[13],part[14],part[15]);
    rowp[4]=make_float4(part[16],part[17],part[18],part[19]);
    rowp[5]=make_float4(part[20],part[21],part[22],part[23]);
    __syncthreads();
    if(t<96){
      int qd = t%6, seg = t/6;
      double a0=0,a1=0,a2=0,a3=0;
      #pragma unroll
      for(int i=0;i<32;i++){
        float4 v = *reinterpret_cast<const float4*>(&sp.p2b[seg*32+i][qd*4]);
        a0+=(double)v.x; a1+=(double)v.y; a2+=(double)v.z; a3+=(double)v.w;
      }
      sp.p3[seg][qd*4+0]=a0; sp.p3[seg][qd*4+1]=a1;
      sp.p3[seg][qd*4+2]=a2; sp.p3[seg][qd*4+3]=a3;
    }
    __syncthreads();
    if(t<24){
      double a=0.0;
      #pragma unroll
      for(int s=0;s<16;s++) a += sp.p3[s][t];
      sp.sMd[t]=a;
    }
    __syncthreads();
    if(t==0) solve24(sp.sMd, sp.curHn, sp.curH, denorm_now, ns1,nm1x,nm1y, ns2,nm2x,nm2y);
    __syncthreads();
  };

  for(int lo=0; lo<5; lo++){
    #pragma unroll
    for(int q=0;q<8;q++){ int p=t+512*q; wreg[q] = sp.inlb[cur][p] ? 1.0f : 0.0f; }
    DLT(false);
    for(int itp=0; itp<4; itp++){
      float Hn[9];
      #pragma unroll
      for(int j=0;j<9;j++) Hn[j]=sp.curHn[j];
      #pragma unroll
      for(int q=0;q<8;q++){
        int p=t+512*q;
        float zn = Hn[6]*X1[q] + Hn[7]*Y1[q] + Hn[8];
        float zi = 1.0f/zn;
        float dx = (Hn[0]*X1[q] + Hn[1]*Y1[q] + Hn[2])*zi - X2[q];
        float dy = (Hn[3]*X1[q] + Hn[4]*Y1[q] + Hn[5])*zi - Y2[q];
        float err = sqrtf(dx*dx + dy*dy + epsn);
        wreg[q] = sp.inlb[cur][p] ? __expf(-err*wk) : 0.0f;
      }
      DLT(itp==3);
    }
    float scoreLo;
    {
      float H[9];
      #pragma unroll
      for(int j=0;j<9;j++) H[j]=sp.curH[j];
      int c=0;
      #pragma unroll
      for(int q=0;q<8;q++){
        int p=t+512*q;
        float e = errsq_f(H, U1[q],V1[q],U2[q],V2[q]);
        unsigned char bb = (e <= 2.0f) ? 1 : 0;
        sp.inlb[cur^1][p] = bb;
        c += bb;
      }
      #pragma unroll
      for(int off=32; off>=1; off>>=1) c += __shfl_down(c, off, 64);
      if(lane==0) sp.redi[wv]=c;
      __syncthreads();
      if(t==0){
        int s=0;
        #pragma unroll
        for(int w8=0;w8<8;w8++) s += sp.redi[w8];
        sp.sScore=(float)s;
      }
      __syncthreads();
      scoreLo = sp.sScore;
    }
    bool better = active && (scoreLo > score);
    if(better){
      if(t<9) sp.sModel[t]=sp.curH[t];
      cur ^= 1;
      score = scoreLo;
    }
    active = better;
    __syncthreads();
    if(!active) break;
  }

  if(t<9) stateF[2+t] = sp.sModel[t];
  #pragma unroll
  for(int q=0;q<8;q++){ int p=t+512*q; best_inl[p] = sp.inlb[cur][p] ? 1.0f : 0.0f; }
  if(t==0){
    stateF[0] = score;
    float ratio = floorf(score) / 4096.0f;
    float r2 = ratio*ratio, r4 = r2*r2;
    float q  = 1.0f - r4;
    q = fminf(fmaxf(q, 1e-12f), (float)(1.0 - 1e-12));
    float max_samp = (score >= 4096.0f) ? 1.0f : (logf(0.01f)/logf(q));
    stateF[1] = (((float)((iter+1)*NBATCH)) >= floorf(max_samp)) ? 1.0f : 0.0f;
  }
}

// ---------------- init (round-5 math, 512 threads) ----------------
__device__ void do_init(ShInit& si, const float* kp1, const float* kp2,
                        float* stateF, float* nrm, float* best_inl,
                        float* p1n, float* p2n){
  const int t = threadIdx.x;
  auto blk_reduce = [&](double v)->double{
    si.red[t]=v; __syncthreads();
    for(int off=256; off>=1; off>>=1){ if(t<off) si.red[t]+=si.red[t+off]; __syncthreads(); }
    double rr = si.red[0]; __syncthreads(); return rr;
  };
  double sx1=0, sy1=0, sx2=0, sy2=0;
  #pragma unroll
  for(int q=0;q<8;q++){
    int p = t + 512*q;
    sx1 += (double)kp1[2*p];   sy1 += (double)kp1[2*p+1];
    sx2 += (double)kp2[2*p];   sy2 += (double)kp2[2*p+1];
  }
  double m1x = blk_reduce(sx1)/(double)NPTS;
  double m1y = blk_reduce(sy1)/(double)NPTS;
  double m2x = blk_reduce(sx2)/(double)NPTS;
  double m2y = blk_reduce(sy2)/(double)NPTS;
  double a1=0, a2=0;
  #pragma unroll
  for(int q=0;q<8;q++){
    int p = t + 512*q;
    double dx1=(double)kp1[2*p]-m1x, dy1=(double)kp1[2*p+1]-m1y;
    double dx2=(double)kp2[2*p]-m2x, dy2=(double)kp2[2*p+1]-m2y;
    a1 += sqrt(dx1*dx1+dy1*dy1);
    a2 += sqrt(dx2*dx2+dy2*dy2);
  }
  double sc1 = blk_reduce(a1)/(double)NPTS;
  double sc2 = blk_reduce(a2)/(double)NPTS;
  double s1 = 1.4142135623730951/(sc1+1e-8);
  double s2 = 1.4142135623730951/(sc2+1e-8);
  if(t==0){
    nrm[0]=(float)s1; nrm[1]=(float)m1x; nrm[2]=(float)m1y;
    nrm[3]=(float)s2; nrm[4]=(float)m2x; nrm[5]=(float)m2y;
    stateF[0]=4.0f; stateF[1]=0.0f;
    for(int j=0;j<9;j++) stateF[2+j]=0.0f;
  }
  #pragma unroll
  for(int q=0;q<8;q++){
    int p = t + 512*q;
    p1n[2*p]   = (float)(s1*((double)kp1[2*p]  -m1x));
    p1n[2*p+1] = (float)(s1*((double)kp1[2*p+1]-m1y));
    p2n[2*p]   = (float)(s2*((double)kp2[2*p]  -m2x));
    p2n[2*p+1] = (float)(s2*((double)kp2[2*p+1]-m2y));
    best_inl[p] = 0.0f;
  }
}

// ---------------- L_it: block 0 = init(it==0) / polish(it-1); blocks 1..1024 = sampling(it)
__global__ __launch_bounds__(TPB) void k_iter(int it, uint32_t key0, uint32_t key1,
                                              const float* __restrict__ kp1,
                                              const float* __restrict__ kp2,
                                              float* __restrict__ ws){
  float* stateF   = ws + 0;      // [0]=best_score [1]=done [2..10]=best_model
  float* nrm      = ws + 16;
  float* best_inl = ws + 32;     // 4096
  float* p1n      = ws + 4128;   // 8192
  float* p2n      = ws + 12320;  // 8192
  float* scoresB  = ws + 20512;  // [2][1024]
  float* modelsB  = ws + 22560;  // [2][1024*9]

  const int b = blockIdx.x;
  const int t = threadIdx.x;
  __shared__ ShAll sh;

  if(b == 0){
    if(it == 0){
      do_init(sh.i, kp1, kp2, stateF, nrm, best_inl, p1n, p2n);
    }else{
      const int pi = it - 1;
      do_polish(sh.p, stateF, nrm, scoresB + (pi&1)*NBATCH,
                modelsB + (pi&1)*NBATCH*9, kp1, kp2, p1n, p2n, best_inl, pi);
    }
    return;
  }

  // -------- sampling block, row r = b-1 --------
  const int r = b - 1;
  if(it > 0){
    if(t==0) sh.s.sdone = (stateF[1] != 0.0f) ? 1 : 0;
    __syncthreads();
    if(sh.s.sdone) return;
  }
  const int lane = t & 63, wv = t >> 6;
  float* scores = scoresB + (it&1)*NBATCH;
  float* models = modelsB + (it&1)*NBATCH*9;

  uint64_t bb[4] = {0ull,0ull,0ull,0ull};
  #pragma unroll
  for(int j=0;j<8;j++){
    int c = t*8 + j;
    uint32_t f = (uint32_t)(r*NPTS + c);
    uint32_t a0,a1;
    tf2x32(key0,key1, 0u, f, a0,a1);
    uint32_t bits = a0 ^ a1;
    uint64_t v = (uint64_t)((bits>>9) + 1u);
    uint64_t kk = (v<<12) | (uint64_t)(4095 - c);
    ins4(bb, kk);
  }
  sh.s.ls2[0][t]=bb[0]; sh.s.ls2[1][t]=bb[1]; sh.s.ls2[2][t]=bb[2]; sh.s.ls2[3][t]=bb[3];
  __syncthreads();
  for(int off=TPB/2; off>=1; off>>=1){
    if(t < off){
      uint64_t o0=sh.s.ls2[0][t+off], o1=sh.s.ls2[1][t+off];
      uint64_t o2=sh.s.ls2[2][t+off], o3=sh.s.ls2[3][t+off];
      ins4(bb,o0); ins4(bb,o1); ins4(bb,o2); ins4(bb,o3);
      sh.s.ls2[0][t]=bb[0]; sh.s.ls2[1][t]=bb[1]; sh.s.ls2[2][t]=bb[2]; sh.s.ls2[3][t]=bb[3];
    }
    __syncthreads();
  }
  if(t==0){
    double P1[4][2], P2[4][2];
    #pragma unroll
    for(int k=0;k<4;k++){
      int id = 4095 - (int)(bb[k] & 0xFFFull);
      P1[k][0]=(double)kp1[2*id]; P1[k][1]=(double)kp1[2*id+1];
      P2[k][0]=(double)kp2[2*id]; P2[k][1]=(double)kp2[2*id+1];
    }
    float Hf[9]; int fl;
    model4(P1,P2,Hf,&fl);
    #pragma unroll
    for(int j=0;j<9;j++){ models[r*9+j]=Hf[j]; sh.s.sH[j]=Hf[j]; }
    sh.s.sFlag = fl;
  }
  __syncthreads();
  float H[9];
  #pragma unroll
  for(int j=0;j<9;j++) H[j]=sh.s.sH[j];
  int cnt=0;
  #pragma unroll
  for(int j=0;j<PPT;j++){
    int p = t + TPB*j;
    float2 a = ((const float2*)kp1)[p];
    float2 c = ((const float2*)kp2)[p];
    float e = errsq_f(H, a.x, a.y, c.x, c.y);
    cnt += (e <= 2.0f) ? 1 : 0;
  }
  #pragma unroll
  for(int off=32; off>=1; off>>=1) cnt += __shfl_down(cnt, off, 64);
  if(lane==0) sh.s.redi[wv]=cnt;
  __syncthreads();
  if(t==0){
    int s=0;
    #pragma unroll
    for(int w8=0;w8<8;w8++) s += sh.s.redi[w8];
    scores[r] = sh.s.sFlag ? (float)s : -1.0f;
  }
}

// ---------------- final: polish(NIT-1) + writeout ----------------
__global__ __launch_bounds__(TPB) void k_fin(const float* __restrict__ kp1,
                                             const float* __restrict__ kp2,
                                             float* __restrict__ out, int out_size,
                                             float* __restrict__ ws){
  float* stateF   = ws + 0;
  float* nrm      = ws + 16;
  float* best_inl = ws + 32;
  float* p1n      = ws + 4128;
  float* p2n      = ws + 12320;
  float* scoresB  = ws + 20512;
  float* modelsB  = ws + 22560;
  const int t = threadIdx.x;
  __shared__ ShAll sh;

  const int pi = NIT - 1;
  do_polish(sh.p, stateF, nrm, scoresB + (pi&1)*NBATCH,
            modelsB + (pi&1)*NBATCH*9, kp1, kp2, p1n, p2n, best_inl, pi);
  __syncthreads();

  if(t<9 && t<out_size) out[t] = stateF[2+t];
  #pragma unroll
  for(int q=0;q<PPT;q++){
    int p = t + TPB*q, o = 9 + p;
    if(o < out_size) out[o] = best_inl[p];
  }
}

// ---------------- host ----------------
extern "C" void kernel_launch(void* const* d_in, const int* in_sizes, int n_in,
                              void* d_out, int out_size, void* d_ws, size_t ws_size,
                              hipStream_t stream) {
  const float* kp1 = (const float*)d_in[0];
  const float* kp2 = (const float*)d_in[1];
  float* out = (float*)d_out;
  float* ws  = (float*)d_ws;

  uint32_t K0h[NIT], K1h[NIT];
  for(int i=0;i<NIT;i++){ uint32_t a,b; tf2x32(0u,42u,0u,(uint32_t)i,a,b); K0h[i]=a; K1h[i]=b; }

  for(int i=0;i<NIT;i++)
    k_iter<<<NBATCH+1, TPB, 0, stream>>>(i, K0h[i], K1h[i], kp1, kp2, ws);
  k_fin<<<1, TPB, 0, stream>>>(kp1, kp2, out, out_size, ws);
}

// Round 12
// 119.128 us; speedup vs baseline: 1.7886x; 1.5064x over previous
//
#include <hip/hip_runtime.h>
#include <cstdint>

#define NPTS   4096
#define NBATCH 1024
#define NIT    10

// ---------------- threefry2x32 (exact JAX rounds) ----------------
__host__ __device__ inline uint32_t rotl32(uint32_t v, uint32_t r){ return (v<<r)|(v>>(32u-r)); }

__host__ __device__ inline void tf2x32(uint32_t k0,uint32_t k1,uint32_t x0,uint32_t x1,
                                       uint32_t&o0,uint32_t&o1){
  uint32_t ks2 = k0 ^ k1 ^ 0x1BD11BDAu;
  x0 += k0; x1 += k1;
  x0+=x1; x1=rotl32(x1,13); x1^=x0;
  x0+=x1; x1=rotl32(x1,15); x1^=x0;
  x0+=x1; x1=rotl32(x1,26); x1^=x0;
  x0+=x1; x1=rotl32(x1, 6); x1^=x0;
  x0+=k1; x1+=ks2+1u;
  x0+=x1; x1=rotl32(x1,17); x1^=x0;
  x0+=x1; x1=rotl32(x1,29); x1^=x0;
  x0+=x1; x1=rotl32(x1,16); x1^=x0;
  x0+=x1; x1=rotl32(x1,24); x1^=x0;
  x0+=ks2; x1+=k0+2u;
  x0+=x1; x1=rotl32(x1,13); x1^=x0;
  x0+=x1; x1=rotl32(x1,15); x1^=x0;
  x0+=x1; x1=rotl32(x1,26); x1^=x0;
  x0+=x1; x1=rotl32(x1, 6); x1^=x0;
  x0+=k0; x1+=k1+3u;
  x0+=x1; x1=rotl32(x1,17); x1^=x0;
  x0+=x1; x1=rotl32(x1,29); x1^=x0;
  x0+=x1; x1=rotl32(x1,16); x1^=x0;
  x0+=x1; x1=rotl32(x1,24); x1^=x0;
  x0+=k1; x1+=ks2+4u;
  x0+=x1; x1=rotl32(x1,13); x1^=x0;
  x0+=x1; x1=rotl32(x1,15); x1^=x0;
  x0+=x1; x1=rotl32(x1,26); x1^=x0;
  x0+=x1; x1=rotl32(x1, 6); x1^=x0;
  x0+=ks2; x1+=k0+5u;
  o0=x0; o1=x1;
}

// ---------------- math helpers ----------------
__device__ inline float errsq_f(const float H[9], float x, float y, float kx, float ky){
  float z  = H[6]*x + H[7]*y + H[8];
  float zi = (fabsf(z) > 1e-8f) ? (1.0f/z) : 1.0f;
  float px = (H[0]*x + H[1]*y + H[2])*zi;
  float py = (H[3]*x + H[4]*y + H[5])*zi;
  float dx = px - kx, dy = py - ky;
  return dx*dx + dy*dy;
}

__device__ inline void denorm_h(const double h[9], double s1, double m1x, double m1y,
                                double s2, double m2x, double m2y, float out[9]){
  double G[3][3];
  #pragma unroll
  for(int r=0;r<3;r++){
    double h0=h[3*r], h1=h[3*r+1], h2=h[3*r+2];
    G[r][0] = h0*s1;
    G[r][1] = h1*s1;
    G[r][2] = -s1*m1x*h0 - s1*m1y*h1 + h2;
  }
  double Hm[3][3];
  double inv2 = 1.0/s2;
  #pragma unroll
  for(int c=0;c<3;c++){
    Hm[0][c] = G[0][c]*inv2 + m2x*G[2][c];
    Hm[1][c] = G[1][c]*inv2 + m2y*G[2][c];
    Hm[2][c] = G[2][c];
  }
  double invd = 1.0/(Hm[2][2] + 1e-8);
  #pragma unroll
  for(int r=0;r<3;r++)
    #pragma unroll
    for(int c=0;c<3;c++)
      out[3*r+c] = (float)(Hm[r][c]*invd);
}

__device__ inline double det3c(double ax,double ay, double bx,double by, double cx,double cy){
  return ax*(by-cy) - bx*(ay-cy) + cx*(ay-by);
}

__device__ inline void h4pt(const double P[4][2], double M[3][3]){
  double c0 = det3c(P[3][0],P[3][1], P[1][0],P[1][1], P[2][0],P[2][1]);
  double c1 = det3c(P[0][0],P[0][1], P[3][0],P[3][1], P[2][0],P[2][1]);
  double c2 = det3c(P[0][0],P[0][1], P[1][0],P[1][1], P[3][0],P[3][1]);
  M[0][0]=c0*P[0][0]; M[0][1]=c1*P[1][0]; M[0][2]=c2*P[2][0];
  M[1][0]=c0*P[0][1]; M[1][1]=c1*P[1][1]; M[1][2]=c2*P[2][1];
  M[2][0]=c0;         M[2][1]=c1;         M[2][2]=c2;
}

__device__ inline void adj3(const double M[3][3], double A[3][3]){
  A[0][0]=M[1][1]*M[2][2]-M[1][2]*M[2][1];
  A[0][1]=M[0][2]*M[2][1]-M[0][1]*M[2][2];
  A[0][2]=M[0][1]*M[1][2]-M[0][2]*M[1][1];
  A[1][0]=M[1][2]*M[2][0]-M[1][0]*M[2][2];
  A[1][1]=M[0][0]*M[2][2]-M[0][2]*M[2][0];
  A[1][2]=M[0][2]*M[1][0]-M[0][0]*M[1][2];
  A[2][0]=M[1][0]*M[2][1]-M[1][1]*M[2][0];
  A[2][1]=M[0][1]*M[2][0]-M[0][0]*M[2][1];
  A[2][2]=M[0][0]*M[1][1]-M[0][1]*M[1][0];
}

__device__ inline void ins4(uint64_t b[4], uint64_t k){
  if(k > b[0]){ b[3]=b[2]; b[2]=b[1]; b[1]=b[0]; b[0]=k; }
  else if(k > b[1]){ b[3]=b[2]; b[2]=b[1]; b[1]=k; }
  else if(k > b[2]){ b[3]=b[2]; b[2]=k; }
  else if(k > b[3]){ b[3]=k; }
}

// symmetric 3x3 explicit inverse (reads lower triangle) — short f64 chain
__device__ inline void inv3sym(const double A[3][3], double R[3][3]){
  double a=A[0][0], b=A[1][0], c=A[2][0], d=A[1][1], e=A[2][1], f=A[2][2];
  double C00=d*f-e*e, C01=c*e-b*f, C02=b*e-c*d;
  double det=a*C00+b*C01+c*C02;
  if(det < 1e-300) det = 1e-300;   // SPD in practice
  double id=1.0/det;
  R[0][0]=C00*id; R[0][1]=C01*id; R[0][2]=C02*id;
  R[1][0]=C01*id; R[1][1]=(a*f-c*c)*id; R[1][2]=(b*c-a*e)*id;
  R[2][0]=C02*id; R[2][1]=R[1][2];      R[2][2]=(a*d-b*b)*id;
}
__device__ inline void mv3(const double M[3][3], const double x[3], double y[3]){
  y[0]=M[0][0]*x[0]+M[0][1]*x[1]+M[0][2]*x[2];
  y[1]=M[1][0]*x[0]+M[1][1]*x[1]+M[1][2]*x[2];
  y[2]=M[2][0]*x[0]+M[2][1]*x[1]+M[2][2]*x[2];
}

// DLT solve from 24 reduced sums, explicit-inverse block solve (f64, one thread)
// HW-validated round 9 (absmax 0.0). ~2.5x shorter dependent chain than Cholesky.
__device__ inline void solve24x(const double* sMd, float curHn[9], float curH[9],
                                bool dnorm, double ns1,double nm1x,double nm1y,
                                double ns2,double nm2x,double nm2y){
  double S0[3][3],S1[3][3],S2[3][3],S3[3][3];
  auto unpackd=[&](const double* s, double M[3][3]){
    M[0][0]=s[0]; M[0][1]=s[1]; M[0][2]=s[3];
    M[1][0]=s[1]; M[1][1]=s[2]; M[1][2]=s[4];
    M[2][0]=s[3]; M[2][1]=s[4]; M[2][2]=s[5];
  };
  unpackd(sMd+0,S0); unpackd(sMd+6,S1); unpackd(sMd+12,S2); unpackd(sMd+18,S3);

  double S0i[3][3]; inv3sym(S0,S0i);
  double T1[3][3], T2[3][3];
  #pragma unroll
  for(int i=0;i<3;i++)
    #pragma unroll
    for(int j=0;j<3;j++){
      T1[i][j]=S0i[i][0]*S1[0][j]+S0i[i][1]*S1[1][j]+S0i[i][2]*S1[2][j];
      T2[i][j]=S0i[i][0]*S2[0][j]+S0i[i][1]*S2[1][j]+S0i[i][2]*S2[2][j];
    }
  double Sc[3][3];
  #pragma unroll
  for(int i=0;i<3;i++)
    #pragma unroll
    for(int j=0;j<3;j++){
      double s = S3[i][j];
      #pragma unroll
      for(int k=0;k<3;k++) s -= S1[i][k]*T1[k][j] + S2[i][k]*T2[k][j];
      Sc[i][j]=s;
    }
  double Sci[3][3]; inv3sym(Sc,Sci);

  double v[9];
  #pragma unroll
  for(int i=0;i<9;i++) v[i]=1.0;
  #pragma unroll
  for(int itn=0; itn<2; itn++){
    double a[3]={v[0],v[1],v[2]}, b[3]={v[3],v[4],v[5]}, c[3]={v[6],v[7],v[8]};
    double w1[3],w2[3];
    mv3(S0i,a,w1); mv3(S0i,b,w2);
    double rhs[3];
    #pragma unroll
    for(int j=0;j<3;j++)
      rhs[j] = c[j] + T1[0][j]*a[0]+T1[1][j]*a[1]+T1[2][j]*a[2]
                    + T2[0][j]*b[0]+T2[1][j]*b[1]+T2[2][j]*b[2];
    double rr[3];
    mv3(Sci,rhs,rr);
    #pragma unroll
    for(int i=0;i<3;i++){
      v[i]   = w1[i] + T1[i][0]*rr[0]+T1[i][1]*rr[1]+T1[i][2]*rr[2];
      v[3+i] = w2[i] + T2[i][0]*rr[0]+T2[i][1]*rr[1]+T2[i][2]*rr[2];
      v[6+i] = rr[i];
    }
    if(itn==0){
      double mx=0.0;
      #pragma unroll
      for(int i=0;i<9;i++){ double aa=fabs(v[i]); if(aa>mx) mx=aa; }
      double sc = 1.0/(mx + 1e-300);
      #pragma unroll
      for(int i=0;i<9;i++) v[i]*=sc;
    }
  }
  double n2=0.0;
  #pragma unroll
  for(int i=0;i<9;i++) n2 += v[i]*v[i];
  double invn = 1.0/sqrt(n2);
  #pragma unroll
  for(int i=0;i<9;i++) v[i]*=invn;
  #pragma unroll
  for(int j=0;j<9;j++) curHn[j]=(float)v[j];
  if(dnorm) denorm_h(v, ns1,nm1x,nm1y, ns2,nm2x,nm2y, curH);
}

__device__ inline void model4(const double P1[4][2], const double P2[4][2],
                              float Hf[9], int* flag){
  const int TRI[4][3] = {{0,1,2},{0,1,3},{0,2,3},{1,2,3}};
  bool valid = true;
  #pragma unroll
  for(int tq=0;tq<4;tq++){
    const int i0=TRI[tq][0], i1=TRI[tq][1], i2=TRI[tq][2];
    double d1 = det3c(P1[i0][0],P1[i0][1], P1[i1][0],P1[i1][1], P1[i2][0],P1[i2][1]);
    double d2 = det3c(P2[i0][0],P2[i0][1], P2[i1][0],P2[i1][1], P2[i2][0],P2[i2][1]);
    int s1 = (d1>0.0)-(d1<0.0), s2 = (d2>0.0)-(d2<0.0);
    if(s1 != s2) valid = false;
  }
  double MA[3][3], MB[3][3], AJ[3][3], H[3][3];
  h4pt(P1, MA); h4pt(P2, MB);
  adj3(MA, AJ);
  #pragma unroll
  for(int i=0;i<3;i++)
    #pragma unroll
    for(int j=0;j<3;j++)
      H[i][j] = MB[i][0]*AJ[0][j] + MB[i][1]*AJ[1][j] + MB[i][2]*AJ[2][j];
  double n2=0.0;
  #pragma unroll
  for(int i=0;i<3;i++)
    #pragma unroll
    for(int j=0;j<3;j++) n2 += H[i][j]*H[i][j];
  double invn = 1.0/sqrt(n2);
  double invd = 1.0/(H[2][2]*invn + 1e-8);
  #pragma unroll
  for(int i=0;i<3;i++)
    #pragma unroll
    for(int j=0;j<3;j++) Hf[3*i+j] = (float)(H[i][j]*invn*invd);
  bool diag_ok = (fminf(fminf(fabsf(Hf[0]),fabsf(Hf[4])),fabsf(Hf[8])) > 1e-4f);
  *flag = (valid && diag_ok) ? 1 : 0;
}

// ---------------- K0: init + full-set normalization (round-5 verbatim) ----------------
__global__ __launch_bounds__(1024) void k_init(const float* __restrict__ kp1,
                                               const float* __restrict__ kp2,
                                               float* stateF, float* nrm,
                                               float* best_inl, float* p1n, float* p2n){
  __shared__ double red[1024];
  const int t = threadIdx.x;
  auto blk_reduce = [&](double v)->double{
    red[t]=v; __syncthreads();
    for(int off=512; off>=1; off>>=1){ if(t<off) red[t]+=red[t+off]; __syncthreads(); }
    double rr = red[0]; __syncthreads(); return rr;
  };
  double sx1=0, sy1=0, sx2=0, sy2=0;
  #pragma unroll
  for(int q=0;q<4;q++){
    int p = t + 1024*q;
    sx1 += (double)kp1[2*p];   sy1 += (double)kp1[2*p+1];
    sx2 += (double)kp2[2*p];   sy2 += (double)kp2[2*p+1];
  }
  double m1x = blk_reduce(sx1)/(double)NPTS;
  double m1y = blk_reduce(sy1)/(double)NPTS;
  double m2x = blk_reduce(sx2)/(double)NPTS;
  double m2y = blk_reduce(sy2)/(double)NPTS;
  double a1=0, a2=0;
  #pragma unroll
  for(int q=0;q<4;q++){
    int p = t + 1024*q;
    double dx1=(double)kp1[2*p]-m1x, dy1=(double)kp1[2*p+1]-m1y;
    double dx2=(double)kp2[2*p]-m2x, dy2=(double)kp2[2*p+1]-m2y;
    a1 += sqrt(dx1*dx1+dy1*dy1);
    a2 += sqrt(dx2*dx2+dy2*dy2);
  }
  double sc1 = blk_reduce(a1)/(double)NPTS;
  double sc2 = blk_reduce(a2)/(double)NPTS;
  double s1 = 1.4142135623730951/(sc1+1e-8);
  double s2 = 1.4142135623730951/(sc2+1e-8);
  if(t==0){
    nrm[0]=(float)s1; nrm[1]=(float)m1x; nrm[2]=(float)m1y;
    nrm[3]=(float)s2; nrm[4]=(float)m2x; nrm[5]=(float)m2y;
    stateF[0]=4.0f; stateF[1]=0.0f;
    for(int j=0;j<9;j++) stateF[2+j]=0.0f;
  }
  #pragma unroll
  for(int q=0;q<4;q++){
    int p = t + 1024*q;
    p1n[2*p]   = (float)(s1*((double)kp1[2*p]  -m1x));
    p1n[2*p+1] = (float)(s1*((double)kp1[2*p+1]-m1y));
    p2n[2*p]   = (float)(s2*((double)kp2[2*p]  -m2x));
    p2n[2*p+1] = (float)(s2*((double)kp2[2*p+1]-m2y));
    best_inl[p] = 0.0f;
  }
}

// ---------------- K1: fused sampling + model + scoring ----------------
// ls2 column-major [4][256]: lane stride 8B = 2-way bank aliasing (free, m136)
// vs round-5's [256][4] 32B stride (16-way conflict).
__global__ __launch_bounds__(256) void k_sample_score(const float* stateF,
                                                uint32_t key0, uint32_t key1,
                                                const float* __restrict__ kp1,
                                                const float* __restrict__ kp2,
                                                float* __restrict__ models,
                                                float* __restrict__ scores){
  if(stateF[1] != 0.0f) return;
  const int r = blockIdx.x;
  const int t = threadIdx.x;
  __shared__ uint64_t ls2[4][256];
  __shared__ float sH[9];
  __shared__ int   sFlag;
  __shared__ int   redi[4];
  uint64_t b[4] = {0ull,0ull,0ull,0ull};
  #pragma unroll
  for(int j=0;j<16;j++){
    int c = t*16 + j;
    uint32_t f = (uint32_t)(r*NPTS + c);
    uint32_t a0,a1;
    tf2x32(key0,key1, 0u, f, a0,a1);
    uint32_t bits = a0 ^ a1;
    uint64_t v = (uint64_t)((bits>>9) + 1u);
    uint64_t key = (v<<12) | (uint64_t)(4095 - c);
    ins4(b, key);
  }
  ls2[0][t]=b[0]; ls2[1][t]=b[1]; ls2[2][t]=b[2]; ls2[3][t]=b[3];
  __syncthreads();
  for(int off=128; off>=1; off>>=1){
    if(t < off){
      uint64_t o0=ls2[0][t+off], o1=ls2[1][t+off], o2=ls2[2][t+off], o3=ls2[3][t+off];
      ins4(b,o0); ins4(b,o1); ins4(b,o2); ins4(b,o3);
      ls2[0][t]=b[0]; ls2[1][t]=b[1]; ls2[2][t]=b[2]; ls2[3][t]=b[3];
    }
    __syncthreads();
  }
  if(t==0){
    double P1[4][2], P2[4][2];
    #pragma unroll
    for(int k=0;k<4;k++){
      int id = 4095 - (int)(b[k] & 0xFFFull);
      P1[k][0]=(double)kp1[2*id]; P1[k][1]=(double)kp1[2*id+1];
      P2[k][0]=(double)kp2[2*id]; P2[k][1]=(double)kp2[2*id+1];
    }
    float Hf[9]; int fl;
    model4(P1,P2,Hf,&fl);
    #pragma unroll
    for(int j=0;j<9;j++){ models[r*9+j]=Hf[j]; sH[j]=Hf[j]; }
    sFlag = fl;
  }
  __syncthreads();
  float H[9];
  #pragma unroll
  for(int j=0;j<9;j++) H[j]=sH[j];
  int cnt=0;
  #pragma unroll
  for(int j=0;j<16;j++){
    int p = t + 256*j;
    float e = errsq_f(H, kp1[2*p], kp1[2*p+1], kp2[2*p], kp2[2*p+1]);
    cnt += (e <= 2.0f) ? 1 : 0;
  }
  #pragma unroll
  for(int off=32; off>=1; off>>=1) cnt += __shfl_down(cnt, off, 64);
  if((t&63)==0) redi[t>>6]=cnt;
  __syncthreads();
  if(t==0) scores[r] = sFlag ? (float)(redi[0]+redi[1]+redi[2]+redi[3]) : -1.0f;
}

// ---------------- K5: argmax + polish (round-5 structure, solve24x) ----------------
__global__ __launch_bounds__(512) void k_polish(float* stateF, const float* nrm,
                                                const float* __restrict__ scores,
                                                const float* __restrict__ models,
                                                const float* __restrict__ kp1,
                                                const float* __restrict__ kp2,
                                                const float* __restrict__ p1n,
                                                const float* __restrict__ p2n,
                                                float* __restrict__ best_inl,
                                                int iter){
  if(stateF[1] != 0.0f) return;
  const int t = threadIdx.x;
  const int lane = t & 63, wv = t >> 6;
  __shared__ float  p2b[512][28];
  __shared__ double p3[16][25];
  __shared__ double sMd[24];
  __shared__ uint64_t redu[8];
  __shared__ int   redi[8];
  __shared__ float sScore;
  __shared__ float sModel[9];
  __shared__ float curHn[9];
  __shared__ float curH[9];
  __shared__ unsigned char inlb[2][NPTS];

  {
    float sA = scores[t], sB = scores[t+512];
    uint64_t kA = ((uint64_t)(uint32_t)(int)(sA + 2.0f) << 12) | (uint64_t)(1023 - t);
    uint64_t kB = ((uint64_t)(uint32_t)(int)(sB + 2.0f) << 12) | (uint64_t)(1023 - (t+512));
    uint64_t k = (kA >= kB) ? kA : kB;
    #pragma unroll
    for(int off=32; off>=1; off>>=1){
      uint64_t o = __shfl_down(k, off, 64);
      if(o > k) k = o;
    }
    if(lane==0) redu[wv]=k;
  }
  __syncthreads();
  if(t==0){
    uint64_t m=redu[0];
    #pragma unroll
    for(int w8=1;w8<8;w8++) if(redu[w8]>m) m=redu[w8];
    redu[0]=m;
  }
  __syncthreads();
  const int bi = 1023 - (int)(redu[0] & 0xFFFull);
  const float selScore = (float)((int)(redu[0] >> 12)) - 2.0f;

  const float bestScore = stateF[0];
  const bool improve = (selScore > bestScore);
  if(!improve) return;

  if(t<9) sModel[t] = models[bi*9+t];
  __syncthreads();

  float U1[8],V1[8],U2[8],V2[8],X1[8],Y1[8],X2[8],Y2[8];
  #pragma unroll
  for(int q=0;q<8;q++){
    int p = t + 512*q;
    U1[q]=kp1[2*p]; V1[q]=kp1[2*p+1];
    U2[q]=kp2[2*p]; V2[q]=kp2[2*p+1];
    X1[q]=p1n[2*p]; Y1[q]=p1n[2*p+1];
    X2[q]=p2n[2*p]; Y2[q]=p2n[2*p+1];
  }
  {
    float H[9];
    #pragma unroll
    for(int j=0;j<9;j++) H[j]=sModel[j];
    #pragma unroll
    for(int q=0;q<8;q++){
      int p = t + 512*q;
      float e = errsq_f(H, U1[q],V1[q],U2[q],V2[q]);
      inlb[0][p] = (e <= 2.0f) ? 1 : 0;
    }
  }
  __syncthreads();

  int cur = 0;
  float score = selScore;
  bool active = true;
  float wreg[8];

  const double ns1=(double)nrm[0], nm1x=(double)nrm[1], nm1y=(double)nrm[2];
  const double ns2=(double)nrm[3], nm2x=(double)nrm[4], nm2y=(double)nrm[5];
  const float s2f  = nrm[3];
  const float epsn = 1e-8f*s2f*s2f;
  const float wk   = 1.0f/(18.0f*s2f);

  auto DLT = [&](bool denorm_now){
    float part[24];
    #pragma unroll
    for(int k=0;k<24;k++) part[k]=0.0f;
    #pragma unroll
    for(int q=0;q<8;q++){
      float w = wreg[q];
      float x=X1[q], y=Y1[q], x2=X2[q], y2=Y2[q];
      float wx = w*x, wy = w*y;
      float m0=wx*x, m1=wx*y, m2=wy*y;
      float s3 = x2*x2 + y2*y2;
      part[0]+=m0; part[1]+=m1; part[2]+=m2; part[3]+=wx; part[4]+=wy; part[5]+=w;
      part[6]+=x2*m0; part[7]+=x2*m1; part[8]+=x2*m2; part[9]+=x2*wx; part[10]+=x2*wy; part[11]+=x2*w;
      part[12]+=y2*m0; part[13]+=y2*m1; part[14]+=y2*m2; part[15]+=y2*wx; part[16]+=y2*wy; part[17]+=y2*w;
      part[18]+=s3*m0; part[19]+=s3*m1; part[20]+=s3*m2; part[21]+=s3*wx; part[22]+=s3*wy; part[23]+=s3*w;
    }
    float4* rowp = reinterpret_cast<float4*>(&p2b[t][0]);
    rowp[0]=make_float4(part[0],part[1],part[2],part[3]);
    rowp[1]=make_float4(part[4],part[5],part[6],part[7]);
    rowp[2]=make_float4(part[8],part[9],part[10],part[11]);
    rowp[3]=make_float4(part[12],part[13],part[14],part[15]);
    rowp[4]=make_float4(part[16],part[17],part[18],part[19]);
    rowp[5]=make_float4(part[20],part[21],part[22],part[23]);
    __syncthreads();
    if(t<96){
      int qd = t%6, seg = t/6;
      double a0=0,a1=0,a2=0,a3=0;
      #pragma unroll
      for(int i=0;i<32;i++){
        float4 v = *reinterpret_cast<const float4*>(&p2b[seg*32+i][qd*4]);
        a0+=(double)v.x; a1+=(double)v.y; a2+=(double)v.z; a3+=(double)v.w;
      }
      p3[seg][qd*4+0]=a0; p3[seg][qd*4+1]=a1; p3[seg][qd*4+2]=a2; p3[seg][qd*4+3]=a3;
    }
    __syncthreads();
    if(t<24){
      double a=0.0;
      #pragma unroll
      for(int s=0;s<16;s++) a += p3[s][t];
      sMd[t]=a;
    }
    __syncthreads();
    if(t==0) solve24x(sMd, curHn, curH, denorm_now, ns1,nm1x,nm1y, ns2,nm2x,nm2y);
    __syncthreads();
  };

  for(int lo=0; lo<5; lo++){
    #pragma unroll
    for(int q=0;q<8;q++){ int p=t+512*q; wreg[q] = inlb[cur][p] ? 1.0f : 0.0f; }
    DLT(false);
    for(int itp=0; itp<4; itp++){
      float Hn[9];
      #pragma unroll
      for(int j=0;j<9;j++) Hn[j]=curHn[j];
      #pragma unroll
      for(int q=0;q<8;q++){
        int p=t+512*q;
        float zn = Hn[6]*X1[q] + Hn[7]*Y1[q] + Hn[8];
        float zi = 1.0f/zn;
        float dx = (Hn[0]*X1[q] + Hn[1]*Y1[q] + Hn[2])*zi - X2[q];
        float dy = (Hn[3]*X1[q] + Hn[4]*Y1[q] + Hn[5])*zi - Y2[q];
        float err = sqrtf(dx*dx + dy*dy + epsn);
        wreg[q] = inlb[cur][p] ? __expf(-err*wk) : 0.0f;
      }
      DLT(itp==3);
    }
    float scoreLo;
    {
      float H[9];
      #pragma unroll
      for(int j=0;j<9;j++) H[j]=curH[j];
      int c=0;
      #pragma unroll
      for(int q=0;q<8;q++){
        int p=t+512*q;
        float e = errsq_f(H, U1[q],V1[q],U2[q],V2[q]);
        unsigned char bb = (e <= 2.0f) ? 1 : 0;
        inlb[cur^1][p] = bb;
        c += bb;
      }
      #pragma unroll
      for(int off=32; off>=1; off>>=1) c += __shfl_down(c, off, 64);
      if(lane==0) redi[wv]=c;
      __syncthreads();
      if(t==0){
        int s=0;
        #pragma unroll
        for(int w8=0;w8<8;w8++) s += redi[w8];
        sScore=(float)s;
      }
      __syncthreads();
      scoreLo = sScore;
    }
    bool better = active && (scoreLo > score);
    if(better){
      if(t<9) sModel[t]=curH[t];
      cur ^= 1;
      score = scoreLo;
    }
    active = better;
    __syncthreads();
    if(!active) break;
  }

  if(t<9) stateF[2+t] = sModel[t];
  #pragma unroll
  for(int q=0;q<8;q++){ int p=t+512*q; best_inl[p] = inlb[cur][p] ? 1.0f : 0.0f; }
  if(t==0){
    stateF[0] = score;
    float ratio = floorf(score) / 4096.0f;
    float r2 = ratio*ratio, r4 = r2*r2;
    float q  = 1.0f - r4;
    q = fminf(fmaxf(q, 1e-12f), (float)(1.0 - 1e-12));
    float max_samp = (score >= 4096.0f) ? 1.0f : (logf(0.01f)/logf(q));
    stateF[1] = (((float)((iter+1)*NBATCH)) >= floorf(max_samp)) ? 1.0f : 0.0f;
  }
}

// ---------------- K6: writeout ----------------
__global__ __launch_bounds__(1024) void k_out(const float* stateF, const float* best_inl,
                                              float* __restrict__ out, int out_size){
  const int t = threadIdx.x;
  if(t<9 && t<out_size) out[t] = stateF[2+t];
  #pragma unroll
  for(int q=0;q<4;q++){
    int p = t + 1024*q, o = 9 + p;
    if(o < out_size) out[o] = best_inl[p];
  }
}

// ---------------- host ----------------
extern "C" void kernel_launch(void* const* d_in, const int* in_sizes, int n_in,
                              void* d_out, int out_size, void* d_ws, size_t ws_size,
                              hipStream_t stream) {
  const float* kp1 = (const float*)d_in[0];
  const float* kp2 = (const float*)d_in[1];
  float* out = (float*)d_out;
  float* ws  = (float*)d_ws;

  // ws layout (floats) — round-5
  float* stateF   = ws + 0;      // 16: [0]=best_score [1]=done [2..10]=best_model
  float* nrm      = ws + 16;     // 8
  float* best_inl = ws + 32;     // 4096
  float* p1n      = ws + 4128;   // 8192
  float* p2n      = ws + 12320;  // 8192
  float* scores   = ws + 20512;  // 1024
  float* models   = ws + 21536;  // 9216

  uint32_t K0h[NIT], K1h[NIT];
  for(int i=0;i<NIT;i++){ uint32_t a,b; tf2x32(0u,42u,0u,(uint32_t)i,a,b); K0h[i]=a; K1h[i]=b; }

  k_init<<<1, 1024, 0, stream>>>(kp1, kp2, stateF, nrm, best_inl, p1n, p2n);
  for(int i=0;i<NIT;i++){
    k_sample_score<<<NBATCH, 256, 0, stream>>>(stateF, K0h[i], K1h[i], kp1, kp2, models, scores);
    k_polish<<<1, 512, 0, stream>>>(stateF, nrm, scores, models, kp1, kp2, p1n, p2n, best_inl, i);
  }
  k_out<<<1, 1024, 0, stream>>>(stateF, best_inl, out, out_size);
}

// Round 13
// 101.366 us; speedup vs baseline: 2.1020x; 1.1752x over previous
//
#include <hip/hip_runtime.h>
#include <cstdint>

#define NPTS   4096
#define NBATCH 1024
#define NIT    10
#define TAILBLK 128
#define ROWSPB  (NBATCH/TAILBLK)   // 8 rows per tail block

// ---------------- threefry2x32 (exact JAX rounds) ----------------
__host__ __device__ inline uint32_t rotl32(uint32_t v, uint32_t r){ return (v<<r)|(v>>(32u-r)); }

__host__ __device__ inline void tf2x32(uint32_t k0,uint32_t k1,uint32_t x0,uint32_t x1,
                                       uint32_t&o0,uint32_t&o1){
  uint32_t ks2 = k0 ^ k1 ^ 0x1BD11BDAu;
  x0 += k0; x1 += k1;
  x0+=x1; x1=rotl32(x1,13); x1^=x0;
  x0+=x1; x1=rotl32(x1,15); x1^=x0;
  x0+=x1; x1=rotl32(x1,26); x1^=x0;
  x0+=x1; x1=rotl32(x1, 6); x1^=x0;
  x0+=k1; x1+=ks2+1u;
  x0+=x1; x1=rotl32(x1,17); x1^=x0;
  x0+=x1; x1=rotl32(x1,29); x1^=x0;
  x0+=x1; x1=rotl32(x1,16); x1^=x0;
  x0+=x1; x1=rotl32(x1,24); x1^=x0;
  x0+=ks2; x1+=k0+2u;
  x0+=x1; x1=rotl32(x1,13); x1^=x0;
  x0+=x1; x1=rotl32(x1,15); x1^=x0;
  x0+=x1; x1=rotl32(x1,26); x1^=x0;
  x0+=x1; x1=rotl32(x1, 6); x1^=x0;
  x0+=k0; x1+=k1+3u;
  x0+=x1; x1=rotl32(x1,17); x1^=x0;
  x0+=x1; x1=rotl32(x1,29); x1^=x0;
  x0+=x1; x1=rotl32(x1,16); x1^=x0;
  x0+=x1; x1=rotl32(x1,24); x1^=x0;
  x0+=k1; x1+=ks2+4u;
  x0+=x1; x1=rotl32(x1,13); x1^=x0;
  x0+=x1; x1=rotl32(x1,15); x1^=x0;
  x0+=x1; x1=rotl32(x1,26); x1^=x0;
  x0+=x1; x1=rotl32(x1, 6); x1^=x0;
  x0+=ks2; x1+=k0+5u;
  o0=x0; o1=x1;
}

// ---------------- math helpers ----------------
__device__ inline float errsq_f(const float H[9], float x, float y, float kx, float ky){
  float z  = H[6]*x + H[7]*y + H[8];
  float zi = (fabsf(z) > 1e-8f) ? (1.0f/z) : 1.0f;
  float px = (H[0]*x + H[1]*y + H[2])*zi;
  float py = (H[3]*x + H[4]*y + H[5])*zi;
  float dx = px - kx, dy = py - ky;
  return dx*dx + dy*dy;
}

__device__ inline void denorm_h(const double h[9], double s1, double m1x, double m1y,
                                double s2, double m2x, double m2y, float out[9]){
  double G[3][3];
  #pragma unroll
  for(int r=0;r<3;r++){
    double h0=h[3*r], h1=h[3*r+1], h2=h[3*r+2];
    G[r][0] = h0*s1;
    G[r][1] = h1*s1;
    G[r][2] = -s1*m1x*h0 - s1*m1y*h1 + h2;
  }
  double Hm[3][3];
  double inv2 = 1.0/s2;
  #pragma unroll
  for(int c=0;c<3;c++){
    Hm[0][c] = G[0][c]*inv2 + m2x*G[2][c];
    Hm[1][c] = G[1][c]*inv2 + m2y*G[2][c];
    Hm[2][c] = G[2][c];
  }
  double invd = 1.0/(Hm[2][2] + 1e-8);
  #pragma unroll
  for(int r=0;r<3;r++)
    #pragma unroll
    for(int c=0;c<3;c++)
      out[3*r+c] = (float)(Hm[r][c]*invd);
}

__device__ inline double det3c(double ax,double ay, double bx,double by, double cx,double cy){
  return ax*(by-cy) - bx*(ay-cy) + cx*(ay-by);
}

__device__ inline void h4pt(const double P[4][2], double M[3][3]){
  double c0 = det3c(P[3][0],P[3][1], P[1][0],P[1][1], P[2][0],P[2][1]);
  double c1 = det3c(P[0][0],P[0][1], P[3][0],P[3][1], P[2][0],P[2][1]);
  double c2 = det3c(P[0][0],P[0][1], P[1][0],P[1][1], P[3][0],P[3][1]);
  M[0][0]=c0*P[0][0]; M[0][1]=c1*P[1][0]; M[0][2]=c2*P[2][0];
  M[1][0]=c0*P[0][1]; M[1][1]=c1*P[1][1]; M[1][2]=c2*P[2][1];
  M[2][0]=c0;         M[2][1]=c1;         M[2][2]=c2;
}

__device__ inline void adj3(const double M[3][3], double A[3][3]){
  A[0][0]=M[1][1]*M[2][2]-M[1][2]*M[2][1];
  A[0][1]=M[0][2]*M[2][1]-M[0][1]*M[2][2];
  A[0][2]=M[0][1]*M[1][2]-M[0][2]*M[1][1];
  A[1][0]=M[1][2]*M[2][0]-M[1][0]*M[2][2];
  A[1][1]=M[0][0]*M[2][2]-M[0][2]*M[2][0];
  A[1][2]=M[0][2]*M[1][0]-M[0][0]*M[1][2];
  A[2][0]=M[1][0]*M[2][1]-M[1][1]*M[2][0];
  A[2][1]=M[0][1]*M[2][0]-M[0][0]*M[2][1];
  A[2][2]=M[0][0]*M[1][1]-M[0][1]*M[1][0];
}

__device__ inline void ins4(uint64_t b[4], uint64_t k){
  if(k > b[0]){ b[3]=b[2]; b[2]=b[1]; b[1]=b[0]; b[0]=k; }
  else if(k > b[1]){ b[3]=b[2]; b[2]=b[1]; b[1]=k; }
  else if(k > b[2]){ b[3]=b[2]; b[2]=k; }
  else if(k > b[3]){ b[3]=k; }
}

__device__ inline void inv3sym(const double A[3][3], double R[3][3]){
  double a=A[0][0], b=A[1][0], c=A[2][0], d=A[1][1], e=A[2][1], f=A[2][2];
  double C00=d*f-e*e, C01=c*e-b*f, C02=b*e-c*d;
  double det=a*C00+b*C01+c*C02;
  if(det < 1e-300) det = 1e-300;
  double id=1.0/det;
  R[0][0]=C00*id; R[0][1]=C01*id; R[0][2]=C02*id;
  R[1][0]=C01*id; R[1][1]=(a*f-c*c)*id; R[1][2]=(b*c-a*e)*id;
  R[2][0]=C02*id; R[2][1]=R[1][2];      R[2][2]=(a*d-b*b)*id;
}
__device__ inline void mv3(const double M[3][3], const double x[3], double y[3]){
  y[0]=M[0][0]*x[0]+M[0][1]*x[1]+M[0][2]*x[2];
  y[1]=M[1][0]*x[0]+M[1][1]*x[1]+M[1][2]*x[2];
  y[2]=M[2][0]*x[0]+M[2][1]*x[1]+M[2][2]*x[2];
}

// DLT solve from 24 reduced sums, explicit-inverse block solve (HW-validated r9/r12)
__device__ inline void solve24x(const double* sMd, float curHn[9], float curH[9],
                                bool dnorm, double ns1,double nm1x,double nm1y,
                                double ns2,double nm2x,double nm2y){
  double S0[3][3],S1[3][3],S2[3][3],S3[3][3];
  auto unpackd=[&](const double* s, double M[3][3]){
    M[0][0]=s[0]; M[0][1]=s[1]; M[0][2]=s[3];
    M[1][0]=s[1]; M[1][1]=s[2]; M[1][2]=s[4];
    M[2][0]=s[3]; M[2][1]=s[4]; M[2][2]=s[5];
  };
  unpackd(sMd+0,S0); unpackd(sMd+6,S1); unpackd(sMd+12,S2); unpackd(sMd+18,S3);

  double S0i[3][3]; inv3sym(S0,S0i);
  double T1[3][3], T2[3][3];
  #pragma unroll
  for(int i=0;i<3;i++)
    #pragma unroll
    for(int j=0;j<3;j++){
      T1[i][j]=S0i[i][0]*S1[0][j]+S0i[i][1]*S1[1][j]+S0i[i][2]*S1[2][j];
      T2[i][j]=S0i[i][0]*S2[0][j]+S0i[i][1]*S2[1][j]+S0i[i][2]*S2[2][j];
    }
  double Sc[3][3];
  #pragma unroll
  for(int i=0;i<3;i++)
    #pragma unroll
    for(int j=0;j<3;j++){
      double s = S3[i][j];
      #pragma unroll
      for(int k=0;k<3;k++) s -= S1[i][k]*T1[k][j] + S2[i][k]*T2[k][j];
      Sc[i][j]=s;
    }
  double Sci[3][3]; inv3sym(Sc,Sci);

  double v[9];
  #pragma unroll
  for(int i=0;i<9;i++) v[i]=1.0;
  #pragma unroll
  for(int itn=0; itn<2; itn++){
    double a[3]={v[0],v[1],v[2]}, b[3]={v[3],v[4],v[5]}, c[3]={v[6],v[7],v[8]};
    double w1[3],w2[3];
    mv3(S0i,a,w1); mv3(S0i,b,w2);
    double rhs[3];
    #pragma unroll
    for(int j=0;j<3;j++)
      rhs[j] = c[j] + T1[0][j]*a[0]+T1[1][j]*a[1]+T1[2][j]*a[2]
                    + T2[0][j]*b[0]+T2[1][j]*b[1]+T2[2][j]*b[2];
    double rr[3];
    mv3(Sci,rhs,rr);
    #pragma unroll
    for(int i=0;i<3;i++){
      v[i]   = w1[i] + T1[i][0]*rr[0]+T1[i][1]*rr[1]+T1[i][2]*rr[2];
      v[3+i] = w2[i] + T2[i][0]*rr[0]+T2[i][1]*rr[1]+T2[i][2]*rr[2];
      v[6+i] = rr[i];
    }
    if(itn==0){
      double mx=0.0;
      #pragma unroll
      for(int i=0;i<9;i++){ double aa=fabs(v[i]); if(aa>mx) mx=aa; }
      double sc = 1.0/(mx + 1e-300);
      #pragma unroll
      for(int i=0;i<9;i++) v[i]*=sc;
    }
  }
  double n2=0.0;
  #pragma unroll
  for(int i=0;i<9;i++) n2 += v[i]*v[i];
  double invn = 1.0/sqrt(n2);
  #pragma unroll
  for(int i=0;i<9;i++) v[i]*=invn;
  #pragma unroll
  for(int j=0;j<9;j++) curHn[j]=(float)v[j];
  if(dnorm) denorm_h(v, ns1,nm1x,nm1y, ns2,nm2x,nm2y, curH);
}

__device__ inline void model4(const double P1[4][2], const double P2[4][2],
                              float Hf[9], int* flag){
  const int TRI[4][3] = {{0,1,2},{0,1,3},{0,2,3},{1,2,3}};
  bool valid = true;
  #pragma unroll
  for(int tq=0;tq<4;tq++){
    const int i0=TRI[tq][0], i1=TRI[tq][1], i2=TRI[tq][2];
    double d1 = det3c(P1[i0][0],P1[i0][1], P1[i1][0],P1[i1][1], P1[i2][0],P1[i2][1]);
    double d2 = det3c(P2[i0][0],P2[i0][1], P2[i1][0],P2[i1][1], P2[i2][0],P2[i2][1]);
    int s1 = (d1>0.0)-(d1<0.0), s2 = (d2>0.0)-(d2<0.0);
    if(s1 != s2) valid = false;
  }
  double MA[3][3], MB[3][3], AJ[3][3], H[3][3];
  h4pt(P1, MA); h4pt(P2, MB);
  adj3(MA, AJ);
  #pragma unroll
  for(int i=0;i<3;i++)
    #pragma unroll
    for(int j=0;j<3;j++)
      H[i][j] = MB[i][0]*AJ[0][j] + MB[i][1]*AJ[1][j] + MB[i][2]*AJ[2][j];
  double n2=0.0;
  #pragma unroll
  for(int i=0;i<3;i++)
    #pragma unroll
    for(int j=0;j<3;j++) n2 += H[i][j]*H[i][j];
  double invn = 1.0/sqrt(n2);
  double invd = 1.0/(H[2][2]*invn + 1e-8);
  #pragma unroll
  for(int i=0;i<3;i++)
    #pragma unroll
    for(int j=0;j<3;j++) Hf[3*i+j] = (float)(H[i][j]*invn*invd);
  bool diag_ok = (fminf(fminf(fabsf(Hf[0]),fabsf(Hf[4])),fabsf(Hf[8])) > 1e-4f);
  *flag = (valid && diag_ok) ? 1 : 0;
}

// ---------------- polish shared state + device function (r12 body) ----------------
struct ShPol {
  float  p2b[512][28];
  double p3[16][25];
  double sMd[24];
  unsigned long long redu[8];
  int    redi[8];
  float  sScore;
  float  sModel[9];
  float  curHn[9];
  float  curH[9];
  unsigned char inlb[2][NPTS];
};

__device__ __forceinline__ void do_polish(ShPol& sp, float* stateF, const float* nrm,
                          const float* scores, const float* models,
                          const float* kp1, const float* kp2,
                          const float* p1n, const float* p2n,
                          float* best_inl, int iter){
  const int t = threadIdx.x;
  const int lane = t & 63, wv = t >> 6;

  if(stateF[1] != 0.0f) return;

  {
    float sA = scores[t], sB = scores[t+512];
    uint64_t kA = ((uint64_t)(uint32_t)(int)(sA + 2.0f) << 12) | (uint64_t)(1023 - t);
    uint64_t kB = ((uint64_t)(uint32_t)(int)(sB + 2.0f) << 12) | (uint64_t)(1023 - (t+512));
    uint64_t k = (kA >= kB) ? kA : kB;
    #pragma unroll
    for(int off=32; off>=1; off>>=1){
      uint64_t o = __shfl_down(k, off, 64);
      if(o > k) k = o;
    }
    if(lane==0) sp.redu[wv]=k;
  }
  __syncthreads();
  if(t==0){
    uint64_t m=sp.redu[0];
    #pragma unroll
    for(int w8=1;w8<8;w8++) if(sp.redu[w8]>m) m=sp.redu[w8];
    sp.redu[0]=m;
  }
  __syncthreads();
  const int bi = 1023 - (int)(sp.redu[0] & 0xFFFull);
  const float selScore = (float)((int)(sp.redu[0] >> 12)) - 2.0f;

  const float bestScore = stateF[0];
  const bool improve = (selScore > bestScore);
  if(!improve) return;

  if(t<9) sp.sModel[t] = models[bi*9+t];
  __syncthreads();

  float U1[8],V1[8],U2[8],V2[8],X1[8],Y1[8],X2[8],Y2[8];
  #pragma unroll
  for(int q=0;q<8;q++){
    int p = t + 512*q;
    U1[q]=kp1[2*p]; V1[q]=kp1[2*p+1];
    U2[q]=kp2[2*p]; V2[q]=kp2[2*p+1];
    X1[q]=p1n[2*p]; Y1[q]=p1n[2*p+1];
    X2[q]=p2n[2*p]; Y2[q]=p2n[2*p+1];
  }
  {
    float H[9];
    #pragma unroll
    for(int j=0;j<9;j++) H[j]=sp.sModel[j];
    #pragma unroll
    for(int q=0;q<8;q++){
      int p = t + 512*q;
      float e = errsq_f(H, U1[q],V1[q],U2[q],V2[q]);
      sp.inlb[0][p] = (e <= 2.0f) ? 1 : 0;
    }
  }
  __syncthreads();

  int cur = 0;
  float score = selScore;
  bool active = true;
  float wreg[8];

  const double ns1=(double)nrm[0], nm1x=(double)nrm[1], nm1y=(double)nrm[2];
  const double ns2=(double)nrm[3], nm2x=(double)nrm[4], nm2y=(double)nrm[5];
  const float s2f  = nrm[3];
  const float epsn = 1e-8f*s2f*s2f;
  const float wk   = 1.0f/(18.0f*s2f);

  auto DLT = [&](bool denorm_now){
    float part[24];
    #pragma unroll
    for(int k=0;k<24;k++) part[k]=0.0f;
    #pragma unroll
    for(int q=0;q<8;q++){
      float w = wreg[q];
      float x=X1[q], y=Y1[q], x2=X2[q], y2=Y2[q];
      float wx = w*x, wy = w*y;
      float m0=wx*x, m1=wx*y, m2=wy*y;
      float s3 = x2*x2 + y2*y2;
      part[0]+=m0; part[1]+=m1; part[2]+=m2; part[3]+=wx; part[4]+=wy; part[5]+=w;
      part[6]+=x2*m0; part[7]+=x2*m1; part[8]+=x2*m2; part[9]+=x2*wx; part[10]+=x2*wy; part[11]+=x2*w;
      part[12]+=y2*m0; part[13]+=y2*m1; part[14]+=y2*m2; part[15]+=y2*wx; part[16]+=y2*wy; part[17]+=y2*w;
      part[18]+=s3*m0; part[19]+=s3*m1; part[20]+=s3*m2; part[21]+=s3*wx; part[22]+=s3*wy; part[23]+=s3*w;
    }
    float4* rowp = reinterpret_cast<float4*>(&sp.p2b[t][0]);
    rowp[0]=make_float4(part[0],part[1],part[2],part[3]);
    rowp[1]=make_float4(part[4],part[5],part[6],part[7]);
    rowp[2]=make_float4(part[8],part[9],part[10],part[11]);
    rowp[3]=make_float4(part[12],part[13],part[14],part[15]);
    rowp[4]=make_float4(part[16],part[17],part[18],part[19]);
    rowp[5]=make_float4(part[20],part[21],part[22],part[23]);
    __syncthreads();
    if(t<96){
      int qd = t%6, seg = t/6;
      double a0=0,a1=0,a2=0,a3=0;
      #pragma unroll
      for(int i=0;i<32;i++){
        float4 v = *reinterpret_cast<const float4*>(&sp.p2b[seg*32+i][qd*4]);
        a0+=(double)v.x; a1+=(double)v.y; a2+=(double)v.z; a3+=(double)v.w;
      }
      sp.p3[seg][qd*4+0]=a0; sp.p3[seg][qd*4+1]=a1;
      sp.p3[seg][qd*4+2]=a2; sp.p3[seg][qd*4+3]=a3;
    }
    __syncthreads();
    if(t<24){
      double a=0.0;
      #pragma unroll
      for(int s=0;s<16;s++) a += sp.p3[s][t];
      sp.sMd[t]=a;
    }
    __syncthreads();
    if(t==0) solve24x(sp.sMd, sp.curHn, sp.curH, denorm_now, ns1,nm1x,nm1y, ns2,nm2x,nm2y);
    __syncthreads();
  };

  for(int lo=0; lo<5; lo++){
    #pragma unroll
    for(int q=0;q<8;q++){ int p=t+512*q; wreg[q] = sp.inlb[cur][p] ? 1.0f : 0.0f; }
    DLT(false);
    for(int itp=0; itp<4; itp++){
      float Hn[9];
      #pragma unroll
      for(int j=0;j<9;j++) Hn[j]=sp.curHn[j];
      #pragma unroll
      for(int q=0;q<8;q++){
        int p=t+512*q;
        float zn = Hn[6]*X1[q] + Hn[7]*Y1[q] + Hn[8];
        float zi = 1.0f/zn;
        float dx = (Hn[0]*X1[q] + Hn[1]*Y1[q] + Hn[2])*zi - X2[q];
        float dy = (Hn[3]*X1[q] + Hn[4]*Y1[q] + Hn[5])*zi - Y2[q];
        float err = sqrtf(dx*dx + dy*dy + epsn);
        wreg[q] = sp.inlb[cur][p] ? __expf(-err*wk) : 0.0f;
      }
      DLT(itp==3);
    }
    float scoreLo;
    {
      float H[9];
      #pragma unroll
      for(int j=0;j<9;j++) H[j]=sp.curH[j];
      int c=0;
      #pragma unroll
      for(int q=0;q<8;q++){
        int p=t+512*q;
        float e = errsq_f(H, U1[q],V1[q],U2[q],V2[q]);
        unsigned char bb = (e <= 2.0f) ? 1 : 0;
        sp.inlb[cur^1][p] = bb;
        c += bb;
      }
      #pragma unroll
      for(int off=32; off>=1; off>>=1) c += __shfl_down(c, off, 64);
      if(lane==0) sp.redi[wv]=c;
      __syncthreads();
      if(t==0){
        int s=0;
        #pragma unroll
        for(int w8=0;w8<8;w8++) s += sp.redi[w8];
        sp.sScore=(float)s;
      }
      __syncthreads();
      scoreLo = sp.sScore;
    }
    bool better = active && (scoreLo > score);
    if(better){
      if(t<9) sp.sModel[t]=sp.curH[t];
      cur ^= 1;
      score = scoreLo;
    }
    active = better;
    __syncthreads();
    if(!active) break;
  }

  if(t<9) stateF[2+t] = sp.sModel[t];
  #pragma unroll
  for(int q=0;q<8;q++){ int p=t+512*q; best_inl[p] = sp.inlb[cur][p] ? 1.0f : 0.0f; }
  if(t==0){
    stateF[0] = score;
    float ratio = floorf(score) / 4096.0f;
    float r2 = ratio*ratio, r4 = r2*r2;
    float q  = 1.0f - r4;
    q = fminf(fmaxf(q, 1e-12f), (float)(1.0 - 1e-12));
    float max_samp = (score >= 4096.0f) ? 1.0f : (logf(0.01f)/logf(q));
    stateF[1] = (((float)((iter+1)*NBATCH)) >= floorf(max_samp)) ? 1.0f : 0.0f;
  }
}

// ---------------- K_ss0: iter-0 sampling (blocks 0..1023) + init (block 1024) ----------------
__global__ __launch_bounds__(256) void k_ss0(uint32_t key0, uint32_t key1,
                                             const float* __restrict__ kp1,
                                             const float* __restrict__ kp2,
                                             float* __restrict__ ws){
  float* stateF   = ws + 0;
  float* nrm      = ws + 16;
  float* best_inl = ws + 32;
  float* p1n      = ws + 4128;
  float* p2n      = ws + 12320;
  float* scores   = ws + 20512;
  float* models   = ws + 21536;

  const int r = blockIdx.x;
  const int t = threadIdx.x;

  if(r == NBATCH){
    // ---- init: 256 threads x 16 points (round-5 math) ----
    __shared__ double red[256];
    auto blk_reduce = [&](double v)->double{
      red[t]=v; __syncthreads();
      for(int off=128; off>=1; off>>=1){ if(t<off) red[t]+=red[t+off]; __syncthreads(); }
      double rr = red[0]; __syncthreads(); return rr;
    };
    double sx1=0, sy1=0, sx2=0, sy2=0;
    #pragma unroll
    for(int q=0;q<16;q++){
      int p = t + 256*q;
      sx1 += (double)kp1[2*p];   sy1 += (double)kp1[2*p+1];
      sx2 += (double)kp2[2*p];   sy2 += (double)kp2[2*p+1];
    }
    double m1x = blk_reduce(sx1)/(double)NPTS;
    double m1y = blk_reduce(sy1)/(double)NPTS;
    double m2x = blk_reduce(sx2)/(double)NPTS;
    double m2y = blk_reduce(sy2)/(double)NPTS;
    double a1=0, a2=0;
    #pragma unroll
    for(int q=0;q<16;q++){
      int p = t + 256*q;
      double dx1=(double)kp1[2*p]-m1x, dy1=(double)kp1[2*p+1]-m1y;
      double dx2=(double)kp2[2*p]-m2x, dy2=(double)kp2[2*p+1]-m2y;
      a1 += sqrt(dx1*dx1+dy1*dy1);
      a2 += sqrt(dx2*dx2+dy2*dy2);
    }
    double sc1 = blk_reduce(a1)/(double)NPTS;
    double sc2 = blk_reduce(a2)/(double)NPTS;
    double s1 = 1.4142135623730951/(sc1+1e-8);
    double s2 = 1.4142135623730951/(sc2+1e-8);
    if(t==0){
      nrm[0]=(float)s1; nrm[1]=(float)m1x; nrm[2]=(float)m1y;
      nrm[3]=(float)s2; nrm[4]=(float)m2x; nrm[5]=(float)m2y;
      stateF[0]=4.0f; stateF[1]=0.0f;
      for(int j=0;j<9;j++) stateF[2+j]=0.0f;
    }
    #pragma unroll
    for(int q=0;q<16;q++){
      int p = t + 256*q;
      p1n[2*p]   = (float)(s1*((double)kp1[2*p]  -m1x));
      p1n[2*p+1] = (float)(s1*((double)kp1[2*p+1]-m1y));
      p2n[2*p]   = (float)(s2*((double)kp2[2*p]  -m2x));
      p2n[2*p+1] = (float)(s2*((double)kp2[2*p+1]-m2y));
      best_inl[p] = 0.0f;
    }
    return;
  }

  // ---- sampling row r (iter 0 — no done check; replay-safe since no state read) ----
  __shared__ uint64_t ls2[4][256];
  __shared__ float sH[9];
  __shared__ int   sFlag;
  __shared__ int   redi[4];
  uint64_t b[4] = {0ull,0ull,0ull,0ull};
  #pragma unroll
  for(int j=0;j<16;j++){
    int c = t*16 + j;
    uint32_t f = (uint32_t)(r*NPTS + c);
    uint32_t a0,a1;
    tf2x32(key0,key1, 0u, f, a0,a1);
    uint32_t bits = a0 ^ a1;
    uint64_t v = (uint64_t)((bits>>9) + 1u);
    uint64_t key = (v<<12) | (uint64_t)(4095 - c);
    ins4(b, key);
  }
  ls2[0][t]=b[0]; ls2[1][t]=b[1]; ls2[2][t]=b[2]; ls2[3][t]=b[3];
  __syncthreads();
  for(int off=128; off>=1; off>>=1){
    if(t < off){
      uint64_t o0=ls2[0][t+off], o1=ls2[1][t+off], o2=ls2[2][t+off], o3=ls2[3][t+off];
      ins4(b,o0); ins4(b,o1); ins4(b,o2); ins4(b,o3);
      ls2[0][t]=b[0]; ls2[1][t]=b[1]; ls2[2][t]=b[2]; ls2[3][t]=b[3];
    }
    __syncthreads();
  }
  if(t==0){
    double P1[4][2], P2[4][2];
    #pragma unroll
    for(int k=0;k<4;k++){
      int id = 4095 - (int)(b[k] & 0xFFFull);
      P1[k][0]=(double)kp1[2*id]; P1[k][1]=(double)kp1[2*id+1];
      P2[k][0]=(double)kp2[2*id]; P2[k][1]=(double)kp2[2*id+1];
    }
    float Hf[9]; int fl;
    model4(P1,P2,Hf,&fl);
    #pragma unroll
    for(int j=0;j<9;j++){ models[r*9+j]=Hf[j]; sH[j]=Hf[j]; }
    sFlag = fl;
  }
  __syncthreads();
  float H[9];
  #pragma unroll
  for(int j=0;j<9;j++) H[j]=sH[j];
  int cnt=0;
  #pragma unroll
  for(int j=0;j<16;j++){
    int p = t + 256*j;
    float e = errsq_f(H, kp1[2*p], kp1[2*p+1], kp2[2*p], kp2[2*p+1]);
    cnt += (e <= 2.0f) ? 1 : 0;
  }
  #pragma unroll
  for(int off=32; off>=1; off>>=1) cnt += __shfl_down(cnt, off, 64);
  if((t&63)==0) redi[t>>6]=cnt;
  __syncthreads();
  if(t==0) scores[r] = sFlag ? (float)(redi[0]+redi[1]+redi[2]+redi[3]) : -1.0f;
}

// ---------------- K_polish: proven standalone polish (iter 0) ----------------
__global__ __launch_bounds__(512) void k_polish(float* stateF, const float* nrm,
                                                const float* __restrict__ scores,
                                                const float* __restrict__ models,
                                                const float* __restrict__ kp1,
                                                const float* __restrict__ kp2,
                                                const float* __restrict__ p1n,
                                                const float* __restrict__ p2n,
                                                float* __restrict__ best_inl,
                                                int iter){
  __shared__ ShPol sp;
  do_polish(sp, stateF, nrm, scores, models, kp1, kp2, p1n, p2n, best_inl, iter);
}

// ---------------- K_tail: iterations 1..9 + writeout, one launch ----------------
struct ShSamp512 {
  unsigned long long ls2[4][512];
  float sH[9];
  int   sFlag;
  int   redi[8];
};
union ShTail { ShPol p; ShSamp512 s; };

// generation grid barrier on workspace memory (zeroed host-side each call).
// Only executed when done==0 (never for the benched input past iter 0).
__device__ inline void gridbar(uint32_t* cnt, uint32_t* gen, uint32_t nblk){
  __threadfence();
  __syncthreads();
  if(threadIdx.x==0){
    uint32_t g = __hip_atomic_load(gen, __ATOMIC_ACQUIRE, __HIP_MEMORY_SCOPE_AGENT);
    uint32_t a = __hip_atomic_fetch_add(cnt, 1u, __ATOMIC_ACQ_REL, __HIP_MEMORY_SCOPE_AGENT);
    if(a == nblk-1u){
      __hip_atomic_store(cnt, 0u, __ATOMIC_RELAXED, __HIP_MEMORY_SCOPE_AGENT);
      __hip_atomic_store(gen, g+1u, __ATOMIC_RELEASE, __HIP_MEMORY_SCOPE_AGENT);
    }else{
      while(__hip_atomic_load(gen, __ATOMIC_ACQUIRE, __HIP_MEMORY_SCOPE_AGENT) == g){
        __builtin_amdgcn_s_sleep(2);
      }
    }
  }
  __syncthreads();
  __threadfence();
}

__global__ __launch_bounds__(512) void k_tail(const float* __restrict__ kp1,
                                              const float* __restrict__ kp2,
                                              float* __restrict__ out, int out_size,
                                              float* __restrict__ ws){
  float* stateF   = ws + 0;
  float* nrm      = ws + 16;
  float* best_inl = ws + 32;
  float* p1n      = ws + 4128;
  float* p2n      = ws + 12320;
  float* scores   = ws + 20512;
  float* models   = ws + 21536;
  uint32_t* barw  = (uint32_t*)(ws + 30752);

  const int b = blockIdx.x;
  const int t = threadIdx.x;
  const int lane = t & 63, wv = t >> 6;
  __shared__ ShTail sh;

  for(int it=1; it<NIT; ++it){
    // uniform done check: stable value (written before kernel for it=1,
    // or before the closing gridbar of the previous iteration).
    float dn = __hip_atomic_load(&stateF[1], __ATOMIC_ACQUIRE, __HIP_MEMORY_SCOPE_AGENT);
    if(dn != 0.0f) break;

    uint32_t key0,key1;
    tf2x32(0u,42u,0u,(uint32_t)it,key0,key1);

    // ---- sample ROWSPB rows (512-thread sampler, r9-validated) ----
    for(int m=0;m<ROWSPB;m++){
      const int r = b*ROWSPB + m;
      uint64_t bb[4] = {0ull,0ull,0ull,0ull};
      #pragma unroll
      for(int j=0;j<8;j++){
        int c = t*8 + j;
        uint32_t f = (uint32_t)(r*NPTS + c);
        uint32_t a0,a1;
        tf2x32(key0,key1, 0u, f, a0,a1);
        uint32_t bits = a0 ^ a1;
        uint64_t v = (uint64_t)((bits>>9) + 1u);
        uint64_t kk = (v<<12) | (uint64_t)(4095 - c);
        ins4(bb, kk);
      }
      sh.s.ls2[0][t]=bb[0]; sh.s.ls2[1][t]=bb[1]; sh.s.ls2[2][t]=bb[2]; sh.s.ls2[3][t]=bb[3];
      __syncthreads();
      for(int off=256; off>=1; off>>=1){
        if(t < off){
          uint64_t o0=sh.s.ls2[0][t+off], o1=sh.s.ls2[1][t+off];
          uint64_t o2=sh.s.ls2[2][t+off], o3=sh.s.ls2[3][t+off];
          ins4(bb,o0); ins4(bb,o1); ins4(bb,o2); ins4(bb,o3);
          sh.s.ls2[0][t]=bb[0]; sh.s.ls2[1][t]=bb[1]; sh.s.ls2[2][t]=bb[2]; sh.s.ls2[3][t]=bb[3];
        }
        __syncthreads();
      }
      if(t==0){
        double P1[4][2], P2[4][2];
        #pragma unroll
        for(int k=0;k<4;k++){
          int id = 4095 - (int)(bb[k] & 0xFFFull);
          P1[k][0]=(double)kp1[2*id]; P1[k][1]=(double)kp1[2*id+1];
          P2[k][0]=(double)kp2[2*id]; P2[k][1]=(double)kp2[2*id+1];
        }
        float Hf[9]; int fl;
        model4(P1,P2,Hf,&fl);
        #pragma unroll
        for(int j=0;j<9;j++){ models[r*9+j]=Hf[j]; sh.s.sH[j]=Hf[j]; }
        sh.s.sFlag = fl;
      }
      __syncthreads();
      float H[9];
      #pragma unroll
      for(int j=0;j<9;j++) H[j]=sh.s.sH[j];
      int cnt=0;
      #pragma unroll
      for(int j=0;j<8;j++){
        int p = t + 512*j;
        float2 a = ((const float2*)kp1)[p];
        float2 c = ((const float2*)kp2)[p];
        float e = errsq_f(H, a.x, a.y, c.x, c.y);
        cnt += (e <= 2.0f) ? 1 : 0;
      }
      #pragma unroll
      for(int off=32; off>=1; off>>=1) cnt += __shfl_down(cnt, off, 64);
      if(lane==0) sh.s.redi[wv]=cnt;
      __syncthreads();
      if(t==0){
        int s=0;
        #pragma unroll
        for(int w8=0;w8<8;w8++) s += sh.s.redi[w8];
        scores[r] = sh.s.sFlag ? (float)s : -1.0f;
      }
      __syncthreads();
    }
    gridbar(&barw[0], &barw[1], (uint32_t)gridDim.x);
    if(b==0) do_polish(sh.p, stateF, nrm, scores, models, kp1, kp2, p1n, p2n, best_inl, it);
    gridbar(&barw[0], &barw[1], (uint32_t)gridDim.x);
  }

  // ---- writeout (block 0; state is final after its loop exit) ----
  if(b==0){
    if(t<9 && t<out_size) out[t] = stateF[2+t];
    #pragma unroll
    for(int q=0;q<8;q++){
      int p = t + 512*q, o = 9 + p;
      if(o < out_size) out[o] = best_inl[p];
    }
  }
}

// ---------------- host ----------------
extern "C" void kernel_launch(void* const* d_in, const int* in_sizes, int n_in,
                              void* d_out, int out_size, void* d_ws, size_t ws_size,
                              hipStream_t stream) {
  const float* kp1 = (const float*)d_in[0];
  const float* kp2 = (const float*)d_in[1];
  float* out = (float*)d_out;
  float* ws  = (float*)d_ws;

  float* stateF   = ws + 0;
  float* nrm      = ws + 16;
  float* best_inl = ws + 32;
  float* p1n      = ws + 4128;
  float* p2n      = ws + 12320;
  float* scores   = ws + 20512;
  float* models   = ws + 21536;
  void*  barw     = (void*)(ws + 30752);

  uint32_t k00, k01;
  tf2x32(0u,42u,0u,0u,k00,k01);

  (void)hipMemsetAsync(barw, 0, 16, stream);
  k_ss0   <<<NBATCH+1, 256, 0, stream>>>(k00, k01, kp1, kp2, ws);
  k_polish<<<1, 512, 0, stream>>>(stateF, nrm, scores, models, kp1, kp2, p1n, p2n, best_inl, 0);
  k_tail  <<<TAILBLK, 512, 0, stream>>>(kp1, kp2, out, out_size, ws);
}